// Round 1
// baseline (2085.131 us; speedup 1.0000x reference)
//
#include <hip/hip_runtime.h>
#include <math.h>

#define S_ 4096
#define V_ 10000
#define E_ 128
#define H_ 256
#define NE_ 4
#define NH_ 4
#define HD_ 64
#define FF_ 2048
#define NL_ 2
#define EPS_ 1e-5f
#define SCALE_ 0.125f

// ---------------- embedding gather ----------------
__global__ __launch_bounds__(256) void k_embed(const int* __restrict__ x,
                                               const float* __restrict__ emb,
                                               float* __restrict__ h) {
  int idx = blockIdx.x * 256 + threadIdx.x;   // S_*E_ total
  int s = idx >> 7;                           // / E_ (=128)
  int e = idx & 127;
  h[idx] = emb[(size_t)x[s] * E_ + e];
}

// ---------------- MoE gates: per-token top-2 softmax vals; token0 -> sel ----------------
__global__ __launch_bounds__(256) void k_gates(const float* __restrict__ X, int din,
                                               const float* __restrict__ gw,
                                               const float* __restrict__ gb,
                                               float* __restrict__ vals,
                                               int* __restrict__ sel) {
  int wave = threadIdx.x >> 6, lane = threadIdx.x & 63;
  int s = blockIdx.x * 4 + wave;
  const float* xs = X + (size_t)s * din;
  float a0 = 0.f, a1 = 0.f, a2 = 0.f, a3 = 0.f;
  for (int i = lane; i < din; i += 64) {
    float xv = xs[i];
    a0 += xv * gw[0 * din + i];
    a1 += xv * gw[1 * din + i];
    a2 += xv * gw[2 * din + i];
    a3 += xv * gw[3 * din + i];
  }
#pragma unroll
  for (int off = 32; off > 0; off >>= 1) {
    a0 += __shfl_xor(a0, off, 64);
    a1 += __shfl_xor(a1, off, 64);
    a2 += __shfl_xor(a2, off, 64);
    a3 += __shfl_xor(a3, off, 64);
  }
  if (lane == 0) {
    float sc[4] = {a0 + gb[0], a1 + gb[1], a2 + gb[2], a3 + gb[3]};
    float mx = fmaxf(fmaxf(sc[0], sc[1]), fmaxf(sc[2], sc[3]));
    float sum = 0.f;
#pragma unroll
    for (int e = 0; e < 4; ++e) { sc[e] = expf(sc[e] - mx); sum += sc[e]; }
    float inv = 1.0f / sum;
#pragma unroll
    for (int e = 0; e < 4; ++e) sc[e] *= inv;
    int i0 = 0; float v0 = sc[0];
#pragma unroll
    for (int e = 1; e < 4; ++e) if (sc[e] > v0) { v0 = sc[e]; i0 = e; }
    float v1 = -1.0f; int i1 = 0;
#pragma unroll
    for (int e = 0; e < 4; ++e) if (e != i0 && sc[e] > v1) { v1 = sc[e]; i1 = e; }
    vals[2 * s + 0] = v0;
    vals[2 * s + 1] = v1;
    if (s == 0) { sel[0] = i0; sel[1] = i1; }
  }
}

// ---------------- MoE expert pair GEMM: Y = v0*(X@W_s0^T+b_s0) + v1*(X@W_s1^T+b_s1) ----------------
__global__ __launch_bounds__(256) void k_moe(const float* __restrict__ X, int din,
                                             const float* __restrict__ ew,
                                             const float* __restrict__ eb,
                                             const float* __restrict__ vals,
                                             const int* __restrict__ sel,
                                             float* __restrict__ Y) {
  __shared__ float As[16][68];
  __shared__ float W0s[16][68];
  __shared__ float W1s[16][68];
  int s0 = sel[0], s1 = sel[1];
  const float* W0 = ew + (size_t)s0 * H_ * din;
  const float* W1 = ew + (size_t)s1 * H_ * din;
  const float* eb0 = eb + (size_t)s0 * H_;
  const float* eb1 = eb + (size_t)s1 * H_;
  int bm = blockIdx.y * 64, bn = blockIdx.x * 64;
  int tid = threadIdx.x;
  int tx = tid & 15, ty = tid >> 4;
  int lr = tid >> 2, lc = (tid & 3) * 4;
  float acc0[4][4] = {}, acc1[4][4] = {};
  for (int k0 = 0; k0 < din; k0 += 16) {
    float4 av = *(const float4*)&X[(size_t)(bm + lr) * din + k0 + lc];
    float4 w0 = *(const float4*)&W0[(size_t)(bn + lr) * din + k0 + lc];
    float4 w1 = *(const float4*)&W1[(size_t)(bn + lr) * din + k0 + lc];
    As[lc + 0][lr] = av.x; As[lc + 1][lr] = av.y; As[lc + 2][lr] = av.z; As[lc + 3][lr] = av.w;
    W0s[lc + 0][lr] = w0.x; W0s[lc + 1][lr] = w0.y; W0s[lc + 2][lr] = w0.z; W0s[lc + 3][lr] = w0.w;
    W1s[lc + 0][lr] = w1.x; W1s[lc + 1][lr] = w1.y; W1s[lc + 2][lr] = w1.z; W1s[lc + 3][lr] = w1.w;
    __syncthreads();
#pragma unroll
    for (int kk = 0; kk < 16; ++kk) {
      float4 a4 = *(const float4*)&As[kk][4 * ty];
      float4 b04 = *(const float4*)&W0s[kk][4 * tx];
      float4 b14 = *(const float4*)&W1s[kk][4 * tx];
      float a[4] = {a4.x, a4.y, a4.z, a4.w};
      float b0[4] = {b04.x, b04.y, b04.z, b04.w};
      float b1[4] = {b14.x, b14.y, b14.z, b14.w};
#pragma unroll
      for (int r = 0; r < 4; ++r)
#pragma unroll
        for (int c = 0; c < 4; ++c) {
          acc0[r][c] += a[r] * b0[c];
          acc1[r][c] += a[r] * b1[c];
        }
    }
    __syncthreads();
  }
#pragma unroll
  for (int r = 0; r < 4; ++r) {
    int row = bm + 4 * ty + r;
    float v0 = vals[2 * row], v1 = vals[2 * row + 1];
    int col = bn + 4 * tx;
    float4 o;
    o.x = v0 * (acc0[r][0] + eb0[col + 0]) + v1 * (acc1[r][0] + eb1[col + 0]);
    o.y = v0 * (acc0[r][1] + eb0[col + 1]) + v1 * (acc1[r][1] + eb1[col + 1]);
    o.z = v0 * (acc0[r][2] + eb0[col + 2]) + v1 * (acc1[r][2] + eb1[col + 2]);
    o.w = v0 * (acc0[r][3] + eb0[col + 3]) + v1 * (acc1[r][3] + eb1[col + 3]);
    *(float4*)&Y[(size_t)row * H_ + col] = o;
  }
}

// ---------------- generic C[M,N] = act(A[M,K] @ W[N,K]^T + bias) ----------------
template <int ACT>
__global__ __launch_bounds__(256) void k_gemm(const float* __restrict__ A,
                                              const float* __restrict__ W,
                                              const float* __restrict__ bias,
                                              float* __restrict__ C,
                                              int M, int N, int K) {
  __shared__ float As[16][68];
  __shared__ float Ws[16][68];
  int bm = blockIdx.y * 64, bn = blockIdx.x * 64;
  int tid = threadIdx.x;
  int tx = tid & 15, ty = tid >> 4;
  int lr = tid >> 2, lc = (tid & 3) * 4;
  int wrow = bn + lr;
  bool wok = wrow < N;
  const float* Wr = W + (size_t)(wok ? wrow : 0) * K;
  const float* Ar = A + (size_t)(bm + lr) * K;
  float acc[4][4] = {};
  for (int k0 = 0; k0 < K; k0 += 16) {
    float4 av = *(const float4*)&Ar[k0 + lc];
    float4 wv = wok ? *(const float4*)&Wr[k0 + lc] : make_float4(0.f, 0.f, 0.f, 0.f);
    As[lc + 0][lr] = av.x; As[lc + 1][lr] = av.y; As[lc + 2][lr] = av.z; As[lc + 3][lr] = av.w;
    Ws[lc + 0][lr] = wv.x; Ws[lc + 1][lr] = wv.y; Ws[lc + 2][lr] = wv.z; Ws[lc + 3][lr] = wv.w;
    __syncthreads();
#pragma unroll
    for (int kk = 0; kk < 16; ++kk) {
      float4 a4 = *(const float4*)&As[kk][4 * ty];
      float4 w4 = *(const float4*)&Ws[kk][4 * tx];
      float a[4] = {a4.x, a4.y, a4.z, a4.w};
      float w[4] = {w4.x, w4.y, w4.z, w4.w};
#pragma unroll
      for (int r = 0; r < 4; ++r)
#pragma unroll
        for (int c = 0; c < 4; ++c) acc[r][c] += a[r] * w[c];
    }
    __syncthreads();
  }
  int col = bn + 4 * tx;
  if (col < N) {
    float b0 = bias[col + 0], b1 = bias[col + 1], b2 = bias[col + 2], b3 = bias[col + 3];
#pragma unroll
    for (int r = 0; r < 4; ++r) {
      int row = bm + 4 * ty + r;
      float4 o;
      o.x = acc[r][0] + b0; o.y = acc[r][1] + b1; o.z = acc[r][2] + b2; o.w = acc[r][3] + b3;
      if (ACT) {
        o.x = fmaxf(o.x, 0.f); o.y = fmaxf(o.y, 0.f);
        o.z = fmaxf(o.z, 0.f); o.w = fmaxf(o.w, 0.f);
      }
      *(float4*)&C[(size_t)row * N + col] = o;
    }
  }
}

// ---------------- flash-style fused attention (one head, BQ=32 query tile) ----------------
__global__ __launch_bounds__(256) void k_attn(const float* __restrict__ qkv,
                                              float* __restrict__ aout) {
  constexpr int BQ = 32, BKV = 64;
  __shared__ float Qs[BQ][HD_ + 1];
  __shared__ float Ks[BKV][HD_ + 1];
  __shared__ float Vs[BKV][HD_];
  __shared__ float Sc[BQ][BKV + 1];
  __shared__ float m_s[BQ], l_s[BQ], mn_s[BQ];
  __shared__ float red[BQ][16];
  int qt = blockIdx.x, head = blockIdx.y;
  int tid = threadIdx.x;
  int tx = tid & 15, ty = tid >> 4;    // thread covers q rows {2ty,2ty+1} x keys {4tx..4tx+3}
  {
    int row = tid >> 3, d0 = (tid & 7) * 8;
    const float* qr = qkv + (size_t)(qt * BQ + row) * (3 * H_) + head * HD_ + d0;
#pragma unroll
    for (int u = 0; u < 8; ++u) Qs[row][d0 + u] = qr[u];
  }
  if (tid < BQ) { m_s[tid] = -1e30f; l_s[tid] = 0.f; }
  float acc[2][4] = {};
  int jr = tid >> 2, kd0 = (tid & 3) * 16;
  for (int kb = 0; kb < S_ / BKV; ++kb) {
    __syncthreads();
    {
      const float* kr = qkv + (size_t)(kb * BKV + jr) * (3 * H_) + H_ + head * HD_ + kd0;
      const float* vr = kr + H_;
#pragma unroll
      for (int u = 0; u < 16; u += 4) {
        float4 kv = *(const float4*)&kr[u];
        float4 vv = *(const float4*)&vr[u];
        Ks[jr][kd0 + u + 0] = kv.x; Ks[jr][kd0 + u + 1] = kv.y;
        Ks[jr][kd0 + u + 2] = kv.z; Ks[jr][kd0 + u + 3] = kv.w;
        Vs[jr][kd0 + u + 0] = vv.x; Vs[jr][kd0 + u + 1] = vv.y;
        Vs[jr][kd0 + u + 2] = vv.z; Vs[jr][kd0 + u + 3] = vv.w;
      }
    }
    __syncthreads();
    float sc[2][4] = {};
#pragma unroll 8
    for (int dd = 0; dd < HD_; ++dd) {
      float q0 = Qs[2 * ty + 0][dd];
      float q1 = Qs[2 * ty + 1][dd];
#pragma unroll
      for (int c = 0; c < 4; ++c) {
        float kv = Ks[4 * tx + c][dd];
        sc[0][c] += q0 * kv;
        sc[1][c] += q1 * kv;
      }
    }
#pragma unroll
    for (int r = 0; r < 2; ++r) {
      float mloc = -1e30f;
#pragma unroll
      for (int c = 0; c < 4; ++c) {
        sc[r][c] *= SCALE_;
        mloc = fmaxf(mloc, sc[r][c]);
      }
      red[2 * ty + r][tx] = mloc;
    }
    __syncthreads();
    if (tid < BQ) {
      float mv = m_s[tid];
#pragma unroll
      for (int u = 0; u < 16; ++u) mv = fmaxf(mv, red[tid][u]);
      mn_s[tid] = mv;
    }
    __syncthreads();
#pragma unroll
    for (int r = 0; r < 2; ++r) {
      int q = 2 * ty + r;
      float mn = mn_s[q];
      float al = __expf(m_s[q] - mn);
      float ps = 0.f;
#pragma unroll
      for (int c = 0; c < 4; ++c) {
        float p = __expf(sc[r][c] - mn);
        Sc[q][4 * tx + c] = p;
        ps += p;
      }
      red[q][tx] = ps;
#pragma unroll
      for (int c = 0; c < 4; ++c) acc[r][c] *= al;
    }
    __syncthreads();
    if (tid < BQ) {
      float sv = 0.f;
#pragma unroll
      for (int u = 0; u < 16; ++u) sv += red[tid][u];
      l_s[tid] = l_s[tid] * __expf(m_s[tid] - mn_s[tid]) + sv;
      m_s[tid] = mn_s[tid];
    }
#pragma unroll 4
    for (int j = 0; j < BKV; ++j) {
      float p0 = Sc[2 * ty + 0][j];
      float p1 = Sc[2 * ty + 1][j];
#pragma unroll
      for (int c = 0; c < 4; ++c) {
        float vv = Vs[j][4 * tx + c];
        acc[0][c] += p0 * vv;
        acc[1][c] += p1 * vv;
      }
    }
  }
  __syncthreads();
#pragma unroll
  for (int r = 0; r < 2; ++r) {
    int q = 2 * ty + r;
    float inv = 1.0f / l_s[q];
    size_t o = (size_t)(qt * BQ + q) * H_ + head * HD_ + 4 * tx;
    float4 ov;
    ov.x = acc[r][0] * inv; ov.y = acc[r][1] * inv;
    ov.z = acc[r][2] * inv; ov.w = acc[r][3] * inv;
    *(float4*)&aout[o] = ov;
  }
}

// ---------------- h = LN(h + t) * g + b, in place ----------------
__global__ __launch_bounds__(256) void k_add_ln(float* __restrict__ h,
                                                const float* __restrict__ t,
                                                const float* __restrict__ g,
                                                const float* __restrict__ b) {
  __shared__ float rbuf[256];
  int s = blockIdx.x, i = threadIdx.x;
  size_t off = (size_t)s * H_ + i;
  float x = h[off] + t[off];
  rbuf[i] = x;
  __syncthreads();
#pragma unroll
  for (int o = 128; o > 0; o >>= 1) {
    if (i < o) rbuf[i] += rbuf[i + o];
    __syncthreads();
  }
  float mean = rbuf[0] * (1.0f / H_);
  __syncthreads();
  float d = x - mean;
  rbuf[i] = d * d;
  __syncthreads();
#pragma unroll
  for (int o = 128; o > 0; o >>= 1) {
    if (i < o) rbuf[i] += rbuf[i + o];
    __syncthreads();
  }
  float var = rbuf[0] * (1.0f / H_);
  h[off] = d * rsqrtf(var + EPS_) * g[i] + b[i];
}

// ---------------- in-place log_softmax over rows of d_out [S,V] ----------------
__global__ __launch_bounds__(256) void k_logsoftmax(float* __restrict__ out) {
  __shared__ float rbuf[256];
  int s = blockIdx.x, t = threadIdx.x;
  float* row = out + (size_t)s * V_;
  float m = -1e30f;
  for (int i = t; i < V_; i += 256) m = fmaxf(m, row[i]);
  rbuf[t] = m;
  __syncthreads();
#pragma unroll
  for (int o = 128; o > 0; o >>= 1) {
    if (t < o) rbuf[t] = fmaxf(rbuf[t], rbuf[t + o]);
    __syncthreads();
  }
  m = rbuf[0];
  __syncthreads();
  float sum = 0.f;
  for (int i = t; i < V_; i += 256) sum += expf(row[i] - m);
  rbuf[t] = sum;
  __syncthreads();
#pragma unroll
  for (int o = 128; o > 0; o >>= 1) {
    if (t < o) rbuf[t] += rbuf[t + o];
    __syncthreads();
  }
  float lse = m + logf(rbuf[0]);
  for (int i = t; i < V_; i += 256) row[i] -= lse;
}

extern "C" void kernel_launch(void* const* d_in, const int* in_sizes, int n_in,
                              void* d_out, int out_size, void* d_ws, size_t ws_size,
                              hipStream_t stream) {
  const int* x = (const int*)d_in[0];
  const float* emb = (const float*)d_in[1];
  const float* moe_gw[3] = {(const float*)d_in[2], (const float*)d_in[6], (const float*)d_in[10]};
  const float* moe_gb[3] = {(const float*)d_in[3], (const float*)d_in[7], (const float*)d_in[11]};
  const float* moe_ew[3] = {(const float*)d_in[4], (const float*)d_in[8], (const float*)d_in[12]};
  const float* moe_eb[3] = {(const float*)d_in[5], (const float*)d_in[9], (const float*)d_in[13]};
  const float* attn_in_w = (const float*)d_in[14];
  const float* attn_in_b = (const float*)d_in[15];
  const float* attn_out_w = (const float*)d_in[16];
  const float* attn_out_b = (const float*)d_in[17];
  const float* ln1_g = (const float*)d_in[18];
  const float* ln1_b = (const float*)d_in[19];
  const float* ln2_g = (const float*)d_in[20];
  const float* ln2_b = (const float*)d_in[21];
  const float* ff1_w = (const float*)d_in[22];
  const float* ff1_b = (const float*)d_in[23];
  const float* ff2_w = (const float*)d_in[24];
  const float* ff2_b = (const float*)d_in[25];
  const float* fc_w = (const float*)d_in[26];
  const float* fc_b = (const float*)d_in[27];
  const float* out_w = (const float*)d_in[28];
  const float* out_b = (const float*)d_in[29];
  float* out = (float*)d_out;

  float* ws = (float*)d_ws;
  float* h_e  = ws;                            // S*E
  float* h_a  = h_e + (size_t)S_ * E_;         // S*H
  float* h_b  = h_a + (size_t)S_ * H_;         // S*H
  float* qkv  = h_b + (size_t)S_ * H_;         // S*3H
  float* ffh  = qkv + (size_t)S_ * 3 * H_;     // S*FF
  float* abuf = ffh + (size_t)S_ * FF_;        // S*H
  float* tmp  = abuf + (size_t)S_ * H_;        // S*H
  float* vals = tmp + (size_t)S_ * H_;         // S*2
  int*   sel  = (int*)(vals + (size_t)S_ * 2); // 2

  k_embed<<<dim3(S_ * E_ / 256), dim3(256), 0, stream>>>(x, emb, h_e);

  k_gates<<<dim3(S_ / 4), dim3(256), 0, stream>>>(h_e, E_, moe_gw[0], moe_gb[0], vals, sel);
  k_moe<<<dim3(H_ / 64, S_ / 64), dim3(256), 0, stream>>>(h_e, E_, moe_ew[0], moe_eb[0], vals, sel, h_a);
  k_gates<<<dim3(S_ / 4), dim3(256), 0, stream>>>(h_a, H_, moe_gw[1], moe_gb[1], vals, sel);
  k_moe<<<dim3(H_ / 64, S_ / 64), dim3(256), 0, stream>>>(h_a, H_, moe_ew[1], moe_eb[1], vals, sel, h_b);
  k_gates<<<dim3(S_ / 4), dim3(256), 0, stream>>>(h_b, H_, moe_gw[2], moe_gb[2], vals, sel);
  k_moe<<<dim3(H_ / 64, S_ / 64), dim3(256), 0, stream>>>(h_b, H_, moe_ew[2], moe_eb[2], vals, sel, h_a);

  for (int l = 0; l < NL_; ++l) {
    k_gemm<0><<<dim3(3 * H_ / 64, S_ / 64), dim3(256), 0, stream>>>(
        h_a, attn_in_w + (size_t)l * 3 * H_ * H_, attn_in_b + (size_t)l * 3 * H_, qkv, S_, 3 * H_, H_);
    k_attn<<<dim3(S_ / 32, NH_), dim3(256), 0, stream>>>(qkv, abuf);
    k_gemm<0><<<dim3(H_ / 64, S_ / 64), dim3(256), 0, stream>>>(
        abuf, attn_out_w + (size_t)l * H_ * H_, attn_out_b + (size_t)l * H_, tmp, S_, H_, H_);
    k_add_ln<<<dim3(S_), dim3(256), 0, stream>>>(h_a, tmp, ln1_g + l * H_, ln1_b + l * H_);
    k_gemm<1><<<dim3(FF_ / 64, S_ / 64), dim3(256), 0, stream>>>(
        h_a, ff1_w + (size_t)l * FF_ * H_, ff1_b + (size_t)l * FF_, ffh, S_, FF_, H_);
    k_gemm<0><<<dim3(H_ / 64, S_ / 64), dim3(256), 0, stream>>>(
        ffh, ff2_w + (size_t)l * H_ * FF_, ff2_b + (size_t)l * H_, tmp, S_, H_, FF_);
    k_add_ln<<<dim3(S_), dim3(256), 0, stream>>>(h_a, tmp, ln2_g + l * H_, ln2_b + l * H_);
  }

  k_gemm<0><<<dim3(H_ / 64, S_ / 64), dim3(256), 0, stream>>>(h_a, fc_w, fc_b, tmp, S_, H_, H_);
  k_gemm<0><<<dim3((V_ + 63) / 64, S_ / 64), dim3(256), 0, stream>>>(tmp, out_w, out_b, out, S_, V_, H_);
  k_logsoftmax<<<dim3(S_), dim3(256), 0, stream>>>(out);
}

// Round 2
// 1218.097 us; speedup vs baseline: 1.7118x; 1.7118x over previous
//
#include <hip/hip_runtime.h>
#include <math.h>

#define S_ 4096
#define V_ 10000
#define E_ 128
#define H_ 256
#define NE_ 4
#define NH_ 4
#define HD_ 64
#define FF_ 2048
#define NL_ 2
#define EPS_ 1e-5f
#define SCALE_ 0.125f

typedef __attribute__((ext_vector_type(8))) short bf16x8;
typedef __attribute__((ext_vector_type(4))) float f32x4;

static __device__ inline short f2bf(float f) {
  unsigned u = __builtin_bit_cast(unsigned, f);
  unsigned r = (u + 0x7fffu + ((u >> 16) & 1u)) >> 16;
  return (short)r;
}

// ---------------- embedding gather ----------------
__global__ __launch_bounds__(256) void k_embed(const int* __restrict__ x,
                                               const float* __restrict__ emb,
                                               float* __restrict__ h) {
  int idx = blockIdx.x * 256 + threadIdx.x;
  int s = idx >> 7;
  int e = idx & 127;
  h[idx] = emb[(size_t)x[s] * E_ + e];
}

// ---------------- MoE gates ----------------
__global__ __launch_bounds__(256) void k_gates(const float* __restrict__ X, int din,
                                               const float* __restrict__ gw,
                                               const float* __restrict__ gb,
                                               float* __restrict__ vals,
                                               int* __restrict__ sel) {
  int wave = threadIdx.x >> 6, lane = threadIdx.x & 63;
  int s = blockIdx.x * 4 + wave;
  const float* xs = X + (size_t)s * din;
  float a0 = 0.f, a1 = 0.f, a2 = 0.f, a3 = 0.f;
  for (int i = lane; i < din; i += 64) {
    float xv = xs[i];
    a0 += xv * gw[0 * din + i];
    a1 += xv * gw[1 * din + i];
    a2 += xv * gw[2 * din + i];
    a3 += xv * gw[3 * din + i];
  }
#pragma unroll
  for (int off = 32; off > 0; off >>= 1) {
    a0 += __shfl_xor(a0, off, 64);
    a1 += __shfl_xor(a1, off, 64);
    a2 += __shfl_xor(a2, off, 64);
    a3 += __shfl_xor(a3, off, 64);
  }
  if (lane == 0) {
    float sc[4] = {a0 + gb[0], a1 + gb[1], a2 + gb[2], a3 + gb[3]};
    float mx = fmaxf(fmaxf(sc[0], sc[1]), fmaxf(sc[2], sc[3]));
    float sum = 0.f;
#pragma unroll
    for (int e = 0; e < 4; ++e) { sc[e] = expf(sc[e] - mx); sum += sc[e]; }
    float inv = 1.0f / sum;
#pragma unroll
    for (int e = 0; e < 4; ++e) sc[e] *= inv;
    int i0 = 0; float v0 = sc[0];
#pragma unroll
    for (int e = 1; e < 4; ++e) if (sc[e] > v0) { v0 = sc[e]; i0 = e; }
    float v1 = -1.0f; int i1 = 0;
#pragma unroll
    for (int e = 0; e < 4; ++e) if (e != i0 && sc[e] > v1) { v1 = sc[e]; i1 = e; }
    vals[2 * s + 0] = v0;
    vals[2 * s + 1] = v1;
    if (s == 0) { sel[0] = i0; sel[1] = i1; }
  }
}

// ---------------- bf16-MFMA GEMM: C[M,N] = epi(A[M,K] @ W[N,K]^T + bias) ----------------
// sel!=null: W += sel[sidx]*N*K, bias += sel[sidx]*N (MoE expert indirection)
// vals!=null: scale (acc+bias) by vals[2*row+sidx]; ADD: accumulate into C.
template <int ACT, int ADD>
__global__ __launch_bounds__(256) void k_gemm(const float* __restrict__ A,
                                              const float* __restrict__ W,
                                              const float* __restrict__ bias_,
                                              float* __restrict__ C,
                                              int M, int N, int K,
                                              const int* __restrict__ sel, int sidx,
                                              const float* __restrict__ vals) {
  __shared__ short As[128][40];   // 80B row stride: 16B-aligned, 2-way banks (free)
  __shared__ short Bs[128][40];
  const float* Wp = W;
  const float* bias = bias_;
  if (sel) { int e = sel[sidx]; Wp += (size_t)e * N * K; bias += (size_t)e * N; }
  int bm = blockIdx.y * 128, bn = blockIdx.x * 128;
  int tid = threadIdx.x, lane = tid & 63, wv = tid >> 6;
  int quad = lane >> 4, m16 = lane & 15;
  int wr = (wv >> 1) * 64, wc = (wv & 1) * 64;
  int srow = tid >> 1, sc0 = (tid & 1) * 16;
  const float* Arow = A + (size_t)(bm + srow) * K;
  int brow = bn + srow;
  const float* Brow = Wp + (size_t)(brow < N ? brow : 0) * K;
  f32x4 acc[4][4];
#pragma unroll
  for (int m = 0; m < 4; ++m)
#pragma unroll
    for (int n = 0; n < 4; ++n) acc[m][n] = (f32x4){0.f, 0.f, 0.f, 0.f};
  for (int k0 = 0; k0 < K; k0 += 32) {
#pragma unroll
    for (int u = 0; u < 4; ++u) {
      float4 a4 = *(const float4*)&Arow[k0 + sc0 + 4 * u];
      short4 s;
      s.x = f2bf(a4.x); s.y = f2bf(a4.y); s.z = f2bf(a4.z); s.w = f2bf(a4.w);
      *(short4*)&As[srow][sc0 + 4 * u] = s;
      float4 b4 = *(const float4*)&Brow[k0 + sc0 + 4 * u];
      short4 t;
      t.x = f2bf(b4.x); t.y = f2bf(b4.y); t.z = f2bf(b4.z); t.w = f2bf(b4.w);
      *(short4*)&Bs[srow][sc0 + 4 * u] = t;
    }
    __syncthreads();
    bf16x8 af[4], bf[4];
#pragma unroll
    for (int m = 0; m < 4; ++m) af[m] = *(const bf16x8*)&As[wr + m * 16 + m16][quad * 8];
#pragma unroll
    for (int n = 0; n < 4; ++n) bf[n] = *(const bf16x8*)&Bs[wc + n * 16 + m16][quad * 8];
#pragma unroll
    for (int m = 0; m < 4; ++m)
#pragma unroll
      for (int n = 0; n < 4; ++n)
        acc[m][n] = __builtin_amdgcn_mfma_f32_16x16x32_bf16(af[m], bf[n], acc[m][n], 0, 0, 0);
    __syncthreads();
  }
#pragma unroll
  for (int n = 0; n < 4; ++n) {
    int col = bn + wc + n * 16 + m16;
    if (col >= N) continue;
    float b = bias[col];
#pragma unroll
    for (int m = 0; m < 4; ++m) {
      int row0 = bm + wr + m * 16 + quad * 4;
#pragma unroll
      for (int r = 0; r < 4; ++r) {
        int row = row0 + r;
        float v = acc[m][n][r] + b;
        if (vals) v *= vals[2 * row + sidx];
        if (ADD) v += C[(size_t)row * N + col];
        if (ACT) v = fmaxf(v, 0.f);
        C[(size_t)row * N + col] = v;
      }
    }
  }
}

// ---------------- bf16-MFMA flash attention ----------------
// Block: 256 threads = 4 waves; wave w owns 16 queries; 64 queries x 1 head per block.
// No max-subtraction: scores here are tiny (|s|<~1), exp is safe, so no rescale pass.
__global__ __launch_bounds__(256) void k_attn(const float* __restrict__ qkv,
                                              float* __restrict__ aout) {
  __shared__ short Ks[64][72];       // [key][d]  144B stride: aligned, 2-way
  __shared__ short Vt[64][72];       // [d][key]
  __shared__ short Ps[4][16][88];    // per-wave P in A-layout; 176B stride: aligned, 2-way
  int tid = threadIdx.x, lane = tid & 63, wv = tid >> 6;
  int quad = lane >> 4, m16 = lane & 15;
  int head = blockIdx.y, hd0 = head * HD_;
  int qbase = blockIdx.x * 64 + wv * 16;
  // Q fragments (held in registers across all KV blocks)
  bf16x8 qf[2];
  {
    const float* qr = qkv + (size_t)(qbase + m16) * (3 * H_) + hd0 + quad * 8;
#pragma unroll
    for (int c = 0; c < 2; ++c) {
      float4 x0 = *(const float4*)&qr[c * 32];
      float4 x1 = *(const float4*)&qr[c * 32 + 4];
      bf16x8 q;
      q[0] = f2bf(x0.x); q[1] = f2bf(x0.y); q[2] = f2bf(x0.z); q[3] = f2bf(x0.w);
      q[4] = f2bf(x1.x); q[5] = f2bf(x1.y); q[6] = f2bf(x1.z); q[7] = f2bf(x1.w);
      qf[c] = q;
    }
  }
  f32x4 o[4];
#pragma unroll
  for (int dt = 0; dt < 4; ++dt) o[dt] = (f32x4){0.f, 0.f, 0.f, 0.f};
  float l[4] = {0.f, 0.f, 0.f, 0.f};

  for (int kb = 0; kb < S_ / 64; ++kb) {
    __syncthreads();
    { // stage K -> Ks[key][d] (bf16)
      int key = tid >> 2, d0 = (tid & 3) * 16;
      const float* kr = qkv + (size_t)(kb * 64 + key) * (3 * H_) + H_ + hd0 + d0;
#pragma unroll
      for (int u = 0; u < 4; ++u) {
        float4 kv = *(const float4*)&kr[4 * u];
        short4 s;
        s.x = f2bf(kv.x); s.y = f2bf(kv.y); s.z = f2bf(kv.z); s.w = f2bf(kv.w);
        *(short4*)&Ks[key][d0 + 4 * u] = s;
      }
    }
    { // stage V transposed -> Vt[d][key] (bf16), 4x4 register transpose
      int key0 = (tid & 15) * 4, d0 = (tid >> 4) * 4;
      const float* vbase = qkv + (size_t)(kb * 64 + key0) * (3 * H_) + 2 * H_ + hd0 + d0;
      float vv[4][4];
#pragma unroll
      for (int i = 0; i < 4; ++i) {
        float4 v4 = *(const float4*)&vbase[(size_t)i * (3 * H_)];
        vv[i][0] = v4.x; vv[i][1] = v4.y; vv[i][2] = v4.z; vv[i][3] = v4.w;
      }
#pragma unroll
      for (int j = 0; j < 4; ++j) {
        short4 s;
        s.x = f2bf(vv[0][j]); s.y = f2bf(vv[1][j]); s.z = f2bf(vv[2][j]); s.w = f2bf(vv[3][j]);
        *(short4*)&Vt[d0 + j][key0] = s;
      }
    }
    __syncthreads();
    // S = Q K^T  (4 key tiles of 16)
    f32x4 s4[4];
#pragma unroll
    for (int kt = 0; kt < 4; ++kt) {
      bf16x8 bk0 = *(const bf16x8*)&Ks[kt * 16 + m16][quad * 8];
      bf16x8 bk1 = *(const bf16x8*)&Ks[kt * 16 + m16][32 + quad * 8];
      f32x4 z = (f32x4){0.f, 0.f, 0.f, 0.f};
      z = __builtin_amdgcn_mfma_f32_16x16x32_bf16(qf[0], bk0, z, 0, 0, 0);
      z = __builtin_amdgcn_mfma_f32_16x16x32_bf16(qf[1], bk1, z, 0, 0, 0);
      s4[kt] = z;
    }
    // P = exp(S*scale); row sums; P -> LDS (A-layout)
    f32x4 rs = (f32x4){0.f, 0.f, 0.f, 0.f};
#pragma unroll
    for (int kt = 0; kt < 4; ++kt) {
#pragma unroll
      for (int r = 0; r < 4; ++r) {
        float p = __expf(s4[kt][r] * SCALE_);
        rs[r] += p;
        Ps[wv][quad * 4 + r][kt * 16 + m16] = f2bf(p);
      }
    }
#pragma unroll
    for (int mask = 1; mask < 16; mask <<= 1) {
      rs[0] += __shfl_xor(rs[0], mask, 16);
      rs[1] += __shfl_xor(rs[1], mask, 16);
      rs[2] += __shfl_xor(rs[2], mask, 16);
      rs[3] += __shfl_xor(rs[3], mask, 16);
    }
#pragma unroll
    for (int r = 0; r < 4; ++r) l[r] += rs[r];
    __syncthreads();  // P written by whole wave before cross-lane read
    // O += P V
#pragma unroll
    for (int c = 0; c < 2; ++c) {
      bf16x8 pa = *(const bf16x8*)&Ps[wv][m16][c * 32 + quad * 8];
#pragma unroll
      for (int dt = 0; dt < 4; ++dt) {
        bf16x8 bv = *(const bf16x8*)&Vt[dt * 16 + m16][c * 32 + quad * 8];
        o[dt] = __builtin_amdgcn_mfma_f32_16x16x32_bf16(pa, bv, o[dt], 0, 0, 0);
      }
    }
  }
  // epilogue: normalize and store fp32
#pragma unroll
  for (int dt = 0; dt < 4; ++dt) {
#pragma unroll
    for (int r = 0; r < 4; ++r) {
      int row = qbase + quad * 4 + r;
      aout[(size_t)row * H_ + hd0 + dt * 16 + m16] = o[dt][r] / l[r];
    }
  }
}

// ---------------- h = LN(h + t) * g + b, in place ----------------
__global__ __launch_bounds__(256) void k_add_ln(float* __restrict__ h,
                                                const float* __restrict__ t,
                                                const float* __restrict__ g,
                                                const float* __restrict__ b) {
  __shared__ float rbuf[256];
  int s = blockIdx.x, i = threadIdx.x;
  size_t off = (size_t)s * H_ + i;
  float x = h[off] + t[off];
  rbuf[i] = x;
  __syncthreads();
#pragma unroll
  for (int o = 128; o > 0; o >>= 1) {
    if (i < o) rbuf[i] += rbuf[i + o];
    __syncthreads();
  }
  float mean = rbuf[0] * (1.0f / H_);
  __syncthreads();
  float d = x - mean;
  rbuf[i] = d * d;
  __syncthreads();
#pragma unroll
  for (int o = 128; o > 0; o >>= 1) {
    if (i < o) rbuf[i] += rbuf[i + o];
    __syncthreads();
  }
  float var = rbuf[0] * (1.0f / H_);
  h[off] = d * rsqrtf(var + EPS_) * g[i] + b[i];
}

// ---------------- in-place log_softmax over rows of d_out [S,V] ----------------
__global__ __launch_bounds__(256) void k_logsoftmax(float* __restrict__ out) {
  __shared__ float rbuf[256];
  int s = blockIdx.x, t = threadIdx.x;
  float* row = out + (size_t)s * V_;
  float m = -1e30f;
  for (int i = t; i < V_; i += 256) m = fmaxf(m, row[i]);
  rbuf[t] = m;
  __syncthreads();
#pragma unroll
  for (int o = 128; o > 0; o >>= 1) {
    if (t < o) rbuf[t] = fmaxf(rbuf[t], rbuf[t + o]);
    __syncthreads();
  }
  m = rbuf[0];
  __syncthreads();
  float sum = 0.f;
  for (int i = t; i < V_; i += 256) sum += expf(row[i] - m);
  rbuf[t] = sum;
  __syncthreads();
#pragma unroll
  for (int o = 128; o > 0; o >>= 1) {
    if (t < o) rbuf[t] += rbuf[t + o];
    __syncthreads();
  }
  float lse = m + logf(rbuf[0]);
  for (int i = t; i < V_; i += 256) row[i] -= lse;
}

extern "C" void kernel_launch(void* const* d_in, const int* in_sizes, int n_in,
                              void* d_out, int out_size, void* d_ws, size_t ws_size,
                              hipStream_t stream) {
  const int* x = (const int*)d_in[0];
  const float* emb = (const float*)d_in[1];
  const float* moe_gw[3] = {(const float*)d_in[2], (const float*)d_in[6], (const float*)d_in[10]};
  const float* moe_gb[3] = {(const float*)d_in[3], (const float*)d_in[7], (const float*)d_in[11]};
  const float* moe_ew[3] = {(const float*)d_in[4], (const float*)d_in[8], (const float*)d_in[12]};
  const float* moe_eb[3] = {(const float*)d_in[5], (const float*)d_in[9], (const float*)d_in[13]};
  const float* attn_in_w = (const float*)d_in[14];
  const float* attn_in_b = (const float*)d_in[15];
  const float* attn_out_w = (const float*)d_in[16];
  const float* attn_out_b = (const float*)d_in[17];
  const float* ln1_g = (const float*)d_in[18];
  const float* ln1_b = (const float*)d_in[19];
  const float* ln2_g = (const float*)d_in[20];
  const float* ln2_b = (const float*)d_in[21];
  const float* ff1_w = (const float*)d_in[22];
  const float* ff1_b = (const float*)d_in[23];
  const float* ff2_w = (const float*)d_in[24];
  const float* ff2_b = (const float*)d_in[25];
  const float* fc_w = (const float*)d_in[26];
  const float* fc_b = (const float*)d_in[27];
  const float* out_w = (const float*)d_in[28];
  const float* out_b = (const float*)d_in[29];
  float* out = (float*)d_out;

  float* ws = (float*)d_ws;
  float* h_e  = ws;                            // S*E
  float* h_a  = h_e + (size_t)S_ * E_;         // S*H
  float* h_b  = h_a + (size_t)S_ * H_;         // S*H
  float* qkv  = h_b + (size_t)S_ * H_;         // S*3H
  float* ffh  = qkv + (size_t)S_ * 3 * H_;     // S*FF
  float* abuf = ffh + (size_t)S_ * FF_;        // S*H
  float* tmp  = abuf + (size_t)S_ * H_;        // S*H
  float* vals = tmp + (size_t)S_ * H_;         // S*2
  int*   sel  = (int*)(vals + (size_t)S_ * 2); // 2

  k_embed<<<dim3(S_ * E_ / 256), dim3(256), 0, stream>>>(x, emb, h_e);

  // MoE stack: gates + two expert GEMM passes (second accumulates)
  const float* moe_in[3] = {h_e, h_a, h_b};
  float* moe_out[3] = {h_a, h_b, h_a};
  int moe_k[3] = {E_, H_, H_};
  for (int i = 0; i < 3; ++i) {
    k_gates<<<dim3(S_ / 4), dim3(256), 0, stream>>>(moe_in[i], moe_k[i], moe_gw[i], moe_gb[i], vals, sel);
    k_gemm<0, 0><<<dim3(H_ / 128, S_ / 128), dim3(256), 0, stream>>>(
        moe_in[i], moe_ew[i], moe_eb[i], moe_out[i], S_, H_, moe_k[i], sel, 0, vals);
    k_gemm<0, 1><<<dim3(H_ / 128, S_ / 128), dim3(256), 0, stream>>>(
        moe_in[i], moe_ew[i], moe_eb[i], moe_out[i], S_, H_, moe_k[i], sel, 1, vals);
  }

  for (int l = 0; l < NL_; ++l) {
    k_gemm<0, 0><<<dim3(3 * H_ / 128, S_ / 128), dim3(256), 0, stream>>>(
        h_a, attn_in_w + (size_t)l * 3 * H_ * H_, attn_in_b + (size_t)l * 3 * H_, qkv,
        S_, 3 * H_, H_, nullptr, 0, nullptr);
    k_attn<<<dim3(S_ / 64, NH_), dim3(256), 0, stream>>>(qkv, abuf);
    k_gemm<0, 0><<<dim3(H_ / 128, S_ / 128), dim3(256), 0, stream>>>(
        abuf, attn_out_w + (size_t)l * H_ * H_, attn_out_b + (size_t)l * H_, tmp,
        S_, H_, H_, nullptr, 0, nullptr);
    k_add_ln<<<dim3(S_), dim3(256), 0, stream>>>(h_a, tmp, ln1_g + l * H_, ln1_b + l * H_);
    k_gemm<1, 0><<<dim3(FF_ / 128, S_ / 128), dim3(256), 0, stream>>>(
        h_a, ff1_w + (size_t)l * FF_ * H_, ff1_b + (size_t)l * FF_, ffh,
        S_, FF_, H_, nullptr, 0, nullptr);
    k_gemm<0, 0><<<dim3(H_ / 128, S_ / 128), dim3(256), 0, stream>>>(
        ffh, ff2_w + (size_t)l * H_ * FF_, ff2_b + (size_t)l * H_, tmp,
        S_, H_, FF_, nullptr, 0, nullptr);
    k_add_ln<<<dim3(S_), dim3(256), 0, stream>>>(h_a, tmp, ln2_g + l * H_, ln2_b + l * H_);
  }

  k_gemm<0, 0><<<dim3(H_ / 128, S_ / 128), dim3(256), 0, stream>>>(
      h_a, fc_w, fc_b, tmp, S_, H_, H_, nullptr, 0, nullptr);
  k_gemm<0, 0><<<dim3((V_ + 127) / 128, S_ / 128), dim3(256), 0, stream>>>(
      tmp, out_w, out_b, out, S_, V_, H_, nullptr, 0, nullptr);
  k_logsoftmax<<<dim3(S_), dim3(256), 0, stream>>>(out);
}

// Round 3
// 665.637 us; speedup vs baseline: 3.1325x; 1.8300x over previous
//
#include <hip/hip_runtime.h>
#include <math.h>

#define S_ 4096
#define V_ 10000
#define E_ 128
#define H_ 256
#define NE_ 4
#define NH_ 4
#define HD_ 64
#define FF_ 2048
#define NL_ 2
#define EPS_ 1e-5f
#define SCALE_ 0.125f
#define SPLITS_ 4

typedef __attribute__((ext_vector_type(8))) short bf16x8;
typedef __attribute__((ext_vector_type(4))) float f32x4;

static __device__ __forceinline__ short f2bf(float f) {
  unsigned u = __builtin_bit_cast(unsigned, f);
  unsigned r = (u + 0x7fffu + ((u >> 16) & 1u)) >> 16;
  return (short)r;
}
static __device__ __forceinline__ float bf2f(short s) {
  unsigned u = ((unsigned)(unsigned short)s) << 16;
  return __builtin_bit_cast(float, u);
}

// ---------------- weight fp32 -> bf16 pre-convert (9 segments, 2048 elems/block) ----------------
struct CvtArgs {
  const float* src[9];
  short* dst[9];
  int pfx[10];
};
__global__ __launch_bounds__(256) void k_cvt(CvtArgs a) {
  int b = blockIdx.x, s = 0;
  while (b >= a.pfx[s + 1]) ++s;
  size_t base = (size_t)(b - a.pfx[s]) * 2048 + threadIdx.x * 8;
  const float* sp = a.src[s] + base;
  short* dp = a.dst[s] + base;
  float4 v0 = *(const float4*)sp;
  float4 v1 = *(const float4*)(sp + 4);
  short4 o0, o1;
  o0.x = f2bf(v0.x); o0.y = f2bf(v0.y); o0.z = f2bf(v0.z); o0.w = f2bf(v0.w);
  o1.x = f2bf(v1.x); o1.y = f2bf(v1.y); o1.z = f2bf(v1.z); o1.w = f2bf(v1.w);
  *(short4*)dp = o0;
  *(short4*)(dp + 4) = o1;
}

// ---------------- embedding gather -> bf16 ----------------
__global__ __launch_bounds__(256) void k_embed(const int* __restrict__ x,
                                               const float* __restrict__ emb,
                                               short* __restrict__ h) {
  int i4 = (blockIdx.x * 256 + threadIdx.x) * 4;
  int s = i4 >> 7, e = i4 & 127;
  float4 v = *(const float4*)&emb[(size_t)x[s] * E_ + e];
  short4 o;
  o.x = f2bf(v.x); o.y = f2bf(v.y); o.z = f2bf(v.z); o.w = f2bf(v.w);
  *(short4*)&h[i4] = o;
}

// ---------------- MoE gates (bf16 input) ----------------
__global__ __launch_bounds__(256) void k_gates(const short* __restrict__ X, int din,
                                               const float* __restrict__ gw,
                                               const float* __restrict__ gb,
                                               float* __restrict__ vals,
                                               int* __restrict__ sel) {
  int wave = threadIdx.x >> 6, lane = threadIdx.x & 63;
  int s = blockIdx.x * 4 + wave;
  const short* xs = X + (size_t)s * din;
  float a0 = 0.f, a1 = 0.f, a2 = 0.f, a3 = 0.f;
  for (int i = lane; i < din; i += 64) {
    float xv = bf2f(xs[i]);
    a0 += xv * gw[0 * din + i];
    a1 += xv * gw[1 * din + i];
    a2 += xv * gw[2 * din + i];
    a3 += xv * gw[3 * din + i];
  }
#pragma unroll
  for (int off = 32; off > 0; off >>= 1) {
    a0 += __shfl_xor(a0, off, 64);
    a1 += __shfl_xor(a1, off, 64);
    a2 += __shfl_xor(a2, off, 64);
    a3 += __shfl_xor(a3, off, 64);
  }
  if (lane == 0) {
    float sc[4] = {a0 + gb[0], a1 + gb[1], a2 + gb[2], a3 + gb[3]};
    float mx = fmaxf(fmaxf(sc[0], sc[1]), fmaxf(sc[2], sc[3]));
    float sum = 0.f;
#pragma unroll
    for (int e = 0; e < 4; ++e) { sc[e] = expf(sc[e] - mx); sum += sc[e]; }
    float inv = 1.0f / sum;
#pragma unroll
    for (int e = 0; e < 4; ++e) sc[e] *= inv;
    int i0 = 0; float v0 = sc[0];
#pragma unroll
    for (int e = 1; e < 4; ++e) if (sc[e] > v0) { v0 = sc[e]; i0 = e; }
    float v1 = -1.0f; int i1 = 0;
#pragma unroll
    for (int e = 0; e < 4; ++e) if (e != i0 && sc[e] > v1) { v1 = sc[e]; i1 = e; }
    vals[2 * s + 0] = v0;
    vals[2 * s + 1] = v1;
    if (s == 0) { sel[0] = i0; sel[1] = i1; }
  }
}

// ---------------- 64x64-tile bf16 GEMM: C = act(A[M,K] @ W[N,K]^T + bias), bf16 out ----------------
template <int ACT>
__global__ __launch_bounds__(256) void k_gemm64(const short* __restrict__ A,
                                                const short* __restrict__ W,
                                                const float* __restrict__ bias,
                                                short* __restrict__ C,
                                                int M, int N, int K) {
  __shared__ short As[64][40];
  __shared__ short Bs[64][40];
  int bm = blockIdx.y * 64, bn = blockIdx.x * 64;
  int tid = threadIdx.x, lane = tid & 63, wv = tid >> 6;
  int quad = lane >> 4, m16 = lane & 15;
  int wr = (wv >> 1) * 32, wc = (wv & 1) * 32;
  int srow = tid >> 2, sc = (tid & 3) * 8;
  const short* Ar = A + (size_t)(bm + srow) * K + sc;
  const short* Wr = W + (size_t)(bn + srow) * K + sc;
  f32x4 acc[2][2];
#pragma unroll
  for (int m = 0; m < 2; ++m)
#pragma unroll
    for (int n = 0; n < 2; ++n) acc[m][n] = (f32x4){0.f, 0.f, 0.f, 0.f};
  for (int k0 = 0; k0 < K; k0 += 32) {
    *(bf16x8*)&As[srow][sc] = *(const bf16x8*)&Ar[k0];
    *(bf16x8*)&Bs[srow][sc] = *(const bf16x8*)&Wr[k0];
    __syncthreads();
    bf16x8 af[2], bf[2];
#pragma unroll
    for (int m = 0; m < 2; ++m) af[m] = *(const bf16x8*)&As[wr + m * 16 + m16][quad * 8];
#pragma unroll
    for (int n = 0; n < 2; ++n) bf[n] = *(const bf16x8*)&Bs[wc + n * 16 + m16][quad * 8];
#pragma unroll
    for (int m = 0; m < 2; ++m)
#pragma unroll
      for (int n = 0; n < 2; ++n)
        acc[m][n] = __builtin_amdgcn_mfma_f32_16x16x32_bf16(af[m], bf[n], acc[m][n], 0, 0, 0);
    __syncthreads();
  }
#pragma unroll
  for (int n = 0; n < 2; ++n) {
    int col = bn + wc + n * 16 + m16;
    float b = bias[col];
#pragma unroll
    for (int m = 0; m < 2; ++m) {
      int row0 = bm + wr + m * 16 + quad * 4;
#pragma unroll
      for (int r = 0; r < 4; ++r) {
        float v = acc[m][n][r] + b;
        if (ACT) v = fmaxf(v, 0.f);
        C[(size_t)(row0 + r) * N + col] = f2bf(v);
      }
    }
  }
}

// ---------------- MoE dual-expert 64x64 GEMM, bf16 out ----------------
__global__ __launch_bounds__(256) void k_moe(const short* __restrict__ A,
                                             const short* __restrict__ EW,
                                             const float* __restrict__ EB,
                                             const float* __restrict__ vals,
                                             const int* __restrict__ sel,
                                             short* __restrict__ C,
                                             int N, int K) {
  __shared__ short As[64][40];
  __shared__ short B0s[64][40];
  __shared__ short B1s[64][40];
  int e0 = sel[0], e1 = sel[1];
  const short* W0 = EW + (size_t)e0 * N * K;
  const short* W1 = EW + (size_t)e1 * N * K;
  const float* b0 = EB + (size_t)e0 * N;
  const float* b1 = EB + (size_t)e1 * N;
  int bm = blockIdx.y * 64, bn = blockIdx.x * 64;
  int tid = threadIdx.x, lane = tid & 63, wv = tid >> 6;
  int quad = lane >> 4, m16 = lane & 15;
  int wr = (wv >> 1) * 32, wc = (wv & 1) * 32;
  int srow = tid >> 2, sc = (tid & 3) * 8;
  const short* Ar = A + (size_t)(bm + srow) * K + sc;
  const short* W0r = W0 + (size_t)(bn + srow) * K + sc;
  const short* W1r = W1 + (size_t)(bn + srow) * K + sc;
  f32x4 a0[2][2], a1[2][2];
#pragma unroll
  for (int m = 0; m < 2; ++m)
#pragma unroll
    for (int n = 0; n < 2; ++n) {
      a0[m][n] = (f32x4){0.f, 0.f, 0.f, 0.f};
      a1[m][n] = (f32x4){0.f, 0.f, 0.f, 0.f};
    }
  for (int k0 = 0; k0 < K; k0 += 32) {
    *(bf16x8*)&As[srow][sc] = *(const bf16x8*)&Ar[k0];
    *(bf16x8*)&B0s[srow][sc] = *(const bf16x8*)&W0r[k0];
    *(bf16x8*)&B1s[srow][sc] = *(const bf16x8*)&W1r[k0];
    __syncthreads();
    bf16x8 af[2], bf0[2], bf1[2];
#pragma unroll
    for (int m = 0; m < 2; ++m) af[m] = *(const bf16x8*)&As[wr + m * 16 + m16][quad * 8];
#pragma unroll
    for (int n = 0; n < 2; ++n) {
      bf0[n] = *(const bf16x8*)&B0s[wc + n * 16 + m16][quad * 8];
      bf1[n] = *(const bf16x8*)&B1s[wc + n * 16 + m16][quad * 8];
    }
#pragma unroll
    for (int m = 0; m < 2; ++m)
#pragma unroll
      for (int n = 0; n < 2; ++n) {
        a0[m][n] = __builtin_amdgcn_mfma_f32_16x16x32_bf16(af[m], bf0[n], a0[m][n], 0, 0, 0);
        a1[m][n] = __builtin_amdgcn_mfma_f32_16x16x32_bf16(af[m], bf1[n], a1[m][n], 0, 0, 0);
      }
    __syncthreads();
  }
#pragma unroll
  for (int n = 0; n < 2; ++n) {
    int col = bn + wc + n * 16 + m16;
    float bb0 = b0[col], bb1 = b1[col];
#pragma unroll
    for (int m = 0; m < 2; ++m) {
      int row0 = bm + wr + m * 16 + quad * 4;
#pragma unroll
      for (int r = 0; r < 4; ++r) {
        int row = row0 + r;
        float v = vals[2 * row] * (a0[m][n][r] + bb0) + vals[2 * row + 1] * (a1[m][n][r] + bb1);
        C[(size_t)row * N + col] = f2bf(v);
      }
    }
  }
}

// ---------------- 128x128-tile bf16 GEMM (ff1 / logits) ----------------
template <int ACT, int F32OUT>
__global__ __launch_bounds__(256) void k_gemm128(const short* __restrict__ A,
                                                 const short* __restrict__ W,
                                                 const float* __restrict__ bias,
                                                 void* __restrict__ Cv,
                                                 int M, int N, int K) {
  __shared__ short As[128][40];
  __shared__ short Bs[128][40];
  int bm = blockIdx.y * 128, bn = blockIdx.x * 128;
  int tid = threadIdx.x, lane = tid & 63, wv = tid >> 6;
  int quad = lane >> 4, m16 = lane & 15;
  int wr = (wv >> 1) * 64, wc = (wv & 1) * 64;
  int srow = tid >> 1, sc = (tid & 1) * 16;
  const short* Ar = A + (size_t)(bm + srow) * K + sc;
  int br = bn + srow;
  const short* Wr = W + (size_t)(br < N ? br : N - 1) * K + sc;
  f32x4 acc[4][4];
#pragma unroll
  for (int m = 0; m < 4; ++m)
#pragma unroll
    for (int n = 0; n < 4; ++n) acc[m][n] = (f32x4){0.f, 0.f, 0.f, 0.f};
  for (int k0 = 0; k0 < K; k0 += 32) {
    *(bf16x8*)&As[srow][sc] = *(const bf16x8*)&Ar[k0];
    *(bf16x8*)&As[srow][sc + 8] = *(const bf16x8*)&Ar[k0 + 8];
    *(bf16x8*)&Bs[srow][sc] = *(const bf16x8*)&Wr[k0];
    *(bf16x8*)&Bs[srow][sc + 8] = *(const bf16x8*)&Wr[k0 + 8];
    __syncthreads();
    bf16x8 af[4], bf[4];
#pragma unroll
    for (int m = 0; m < 4; ++m) af[m] = *(const bf16x8*)&As[wr + m * 16 + m16][quad * 8];
#pragma unroll
    for (int n = 0; n < 4; ++n) bf[n] = *(const bf16x8*)&Bs[wc + n * 16 + m16][quad * 8];
#pragma unroll
    for (int m = 0; m < 4; ++m)
#pragma unroll
      for (int n = 0; n < 4; ++n)
        acc[m][n] = __builtin_amdgcn_mfma_f32_16x16x32_bf16(af[m], bf[n], acc[m][n], 0, 0, 0);
    __syncthreads();
  }
#pragma unroll
  for (int n = 0; n < 4; ++n) {
    int col = bn + wc + n * 16 + m16;
    if (col >= N) continue;
    float b = bias[col];
#pragma unroll
    for (int m = 0; m < 4; ++m) {
      int row0 = bm + wr + m * 16 + quad * 4;
#pragma unroll
      for (int r = 0; r < 4; ++r) {
        float v = acc[m][n][r] + b;
        if (ACT) v = fmaxf(v, 0.f);
        if (F32OUT)
          ((float*)Cv)[(size_t)(row0 + r) * N + col] = v;
        else
          ((short*)Cv)[(size_t)(row0 + r) * N + col] = f2bf(v);
      }
    }
  }
}

// ---------------- bf16-MFMA flash attention, KV-split; unnormalized fp32 partials ----------------
__global__ __launch_bounds__(256) void k_attn(const short* __restrict__ qkv,
                                              float* __restrict__ Opart,
                                              float* __restrict__ Lpart) {
  __shared__ short Ks[64][72];
  __shared__ short Vt[64][72];
  __shared__ short Ps[4][16][88];
  int tid = threadIdx.x, lane = tid & 63, wv = tid >> 6;
  int quad = lane >> 4, m16 = lane & 15;
  int head = blockIdx.y, hd0 = head * HD_;
  int split = blockIdx.z;
  int qbase = blockIdx.x * 64 + wv * 16;
  bf16x8 qf[2];
  {
    const short* qr = qkv + (size_t)(qbase + m16) * (3 * H_) + hd0 + quad * 8;
    qf[0] = *(const bf16x8*)&qr[0];
    qf[1] = *(const bf16x8*)&qr[32];
  }
  f32x4 o[4];
#pragma unroll
  for (int dt = 0; dt < 4; ++dt) o[dt] = (f32x4){0.f, 0.f, 0.f, 0.f};
  float l[4] = {0.f, 0.f, 0.f, 0.f};

  int kb_end = (split + 1) * (S_ / 64 / SPLITS_);
  for (int kb = split * (S_ / 64 / SPLITS_); kb < kb_end; ++kb) {
    __syncthreads();
    { // stage K
      int key = tid >> 2, d0 = (tid & 3) * 16;
      const short* kr = qkv + (size_t)(kb * 64 + key) * (3 * H_) + H_ + hd0 + d0;
      *(bf16x8*)&Ks[key][d0] = *(const bf16x8*)&kr[0];
      *(bf16x8*)&Ks[key][d0 + 8] = *(const bf16x8*)&kr[8];
    }
    { // stage V transposed (4x4 register transpose)
      int key0 = (tid & 15) * 4, d0 = (tid >> 4) * 4;
      const short* vbase = qkv + (size_t)(kb * 64 + key0) * (3 * H_) + 2 * H_ + hd0 + d0;
      short4 v0 = *(const short4*)&vbase[0];
      short4 v1 = *(const short4*)&vbase[3 * H_];
      short4 v2 = *(const short4*)&vbase[6 * H_];
      short4 v3 = *(const short4*)&vbase[9 * H_];
      short4 t0 = {v0.x, v1.x, v2.x, v3.x};
      short4 t1 = {v0.y, v1.y, v2.y, v3.y};
      short4 t2 = {v0.z, v1.z, v2.z, v3.z};
      short4 t3 = {v0.w, v1.w, v2.w, v3.w};
      *(short4*)&Vt[d0 + 0][key0] = t0;
      *(short4*)&Vt[d0 + 1][key0] = t1;
      *(short4*)&Vt[d0 + 2][key0] = t2;
      *(short4*)&Vt[d0 + 3][key0] = t3;
    }
    __syncthreads();
    // S = Q K^T
    f32x4 s4[4];
#pragma unroll
    for (int kt = 0; kt < 4; ++kt) {
      bf16x8 bk0 = *(const bf16x8*)&Ks[kt * 16 + m16][quad * 8];
      bf16x8 bk1 = *(const bf16x8*)&Ks[kt * 16 + m16][32 + quad * 8];
      f32x4 z = (f32x4){0.f, 0.f, 0.f, 0.f};
      z = __builtin_amdgcn_mfma_f32_16x16x32_bf16(qf[0], bk0, z, 0, 0, 0);
      z = __builtin_amdgcn_mfma_f32_16x16x32_bf16(qf[1], bk1, z, 0, 0, 0);
      s4[kt] = z;
    }
    // P = exp(S*scale) (no max-subtraction: scores are small); row sums
    f32x4 rs = (f32x4){0.f, 0.f, 0.f, 0.f};
#pragma unroll
    for (int kt = 0; kt < 4; ++kt) {
#pragma unroll
      for (int r = 0; r < 4; ++r) {
        float p = __expf(s4[kt][r] * SCALE_);
        rs[r] += p;
        Ps[wv][quad * 4 + r][kt * 16 + m16] = f2bf(p);
      }
    }
#pragma unroll
    for (int mask = 1; mask < 16; mask <<= 1) {
      rs[0] += __shfl_xor(rs[0], mask, 16);
      rs[1] += __shfl_xor(rs[1], mask, 16);
      rs[2] += __shfl_xor(rs[2], mask, 16);
      rs[3] += __shfl_xor(rs[3], mask, 16);
    }
#pragma unroll
    for (int r = 0; r < 4; ++r) l[r] += rs[r];
    // O += P V   (Ps is per-wave; in-wave DS ordering makes this safe without barrier)
#pragma unroll
    for (int c = 0; c < 2; ++c) {
      bf16x8 pa = *(const bf16x8*)&Ps[wv][m16][c * 32 + quad * 8];
#pragma unroll
      for (int dt = 0; dt < 4; ++dt) {
        bf16x8 bv = *(const bf16x8*)&Vt[dt * 16 + m16][c * 32 + quad * 8];
        o[dt] = __builtin_amdgcn_mfma_f32_16x16x32_bf16(pa, bv, o[dt], 0, 0, 0);
      }
    }
  }
  // write unnormalized partials
  float* Op = Opart + ((size_t)(split * NH_ + head) * S_) * 64;
#pragma unroll
  for (int dt = 0; dt < 4; ++dt) {
#pragma unroll
    for (int r = 0; r < 4; ++r) {
      int row = qbase + quad * 4 + r;
      Op[(size_t)row * 64 + dt * 16 + m16] = o[dt][r];
    }
  }
  if (m16 == 0) {
    float* Lp = Lpart + (size_t)(split * NH_ + head) * S_;
#pragma unroll
    for (int r = 0; r < 4; ++r) Lp[qbase + quad * 4 + r] = l[r];
  }
}

// ---------------- combine split partials -> abuf bf16 ----------------
__global__ __launch_bounds__(256) void k_att_combine(const float* __restrict__ Opart,
                                                     const float* __restrict__ Lpart,
                                                     short* __restrict__ abuf) {
  int idx = blockIdx.x * 256 + threadIdx.x;  // over S_*H_
  int s = idx >> 8, hd = idx & 255;
  int head = hd >> 6, d = hd & 63;
  float num = 0.f, den = 0.f;
#pragma unroll
  for (int sp = 0; sp < SPLITS_; ++sp) {
    num += Opart[((size_t)(sp * NH_ + head) * S_ + s) * 64 + d];
    den += Lpart[(size_t)(sp * NH_ + head) * S_ + s];
  }
  abuf[idx] = f2bf(num / den);
}

// ---------------- h = LN(h + t) * g + b (bf16 in/out) ----------------
__global__ __launch_bounds__(256) void k_add_ln(short* __restrict__ h,
                                                const short* __restrict__ t,
                                                const float* __restrict__ g,
                                                const float* __restrict__ b) {
  __shared__ float rbuf[256];
  int s = blockIdx.x, i = threadIdx.x;
  size_t off = (size_t)s * H_ + i;
  float x = bf2f(h[off]) + bf2f(t[off]);
  rbuf[i] = x;
  __syncthreads();
#pragma unroll
  for (int o = 128; o > 0; o >>= 1) {
    if (i < o) rbuf[i] += rbuf[i + o];
    __syncthreads();
  }
  float mean = rbuf[0] * (1.0f / H_);
  __syncthreads();
  float d = x - mean;
  rbuf[i] = d * d;
  __syncthreads();
#pragma unroll
  for (int o = 128; o > 0; o >>= 1) {
    if (i < o) rbuf[i] += rbuf[i + o];
    __syncthreads();
  }
  float var = rbuf[0] * (1.0f / H_);
  h[off] = f2bf(d * rsqrtf(var + EPS_) * g[i] + b[i]);
}

// ---------------- in-place log_softmax over rows of d_out [S,V] ----------------
__global__ __launch_bounds__(256) void k_logsoftmax(float* __restrict__ out) {
  __shared__ float rbuf[256];
  int s = blockIdx.x, t = threadIdx.x;
  float* row = out + (size_t)s * V_;
  float m = -1e30f;
  for (int i = t; i < V_; i += 256) m = fmaxf(m, row[i]);
  rbuf[t] = m;
  __syncthreads();
#pragma unroll
  for (int o = 128; o > 0; o >>= 1) {
    if (t < o) rbuf[t] = fmaxf(rbuf[t], rbuf[t + o]);
    __syncthreads();
  }
  m = rbuf[0];
  __syncthreads();
  float sum = 0.f;
  for (int i = t; i < V_; i += 256) sum += expf(row[i] - m);
  rbuf[t] = sum;
  __syncthreads();
#pragma unroll
  for (int o = 128; o > 0; o >>= 1) {
    if (t < o) rbuf[t] += rbuf[t + o];
    __syncthreads();
  }
  float lse = m + logf(rbuf[0]);
  for (int i = t; i < V_; i += 256) row[i] -= lse;
}

extern "C" void kernel_launch(void* const* d_in, const int* in_sizes, int n_in,
                              void* d_out, int out_size, void* d_ws, size_t ws_size,
                              hipStream_t stream) {
  const int* x = (const int*)d_in[0];
  const float* emb = (const float*)d_in[1];
  const float* moe_gw[3] = {(const float*)d_in[2], (const float*)d_in[6], (const float*)d_in[10]};
  const float* moe_gb[3] = {(const float*)d_in[3], (const float*)d_in[7], (const float*)d_in[11]};
  const float* moe_eb[3] = {(const float*)d_in[5], (const float*)d_in[9], (const float*)d_in[13]};
  const float* attn_in_b = (const float*)d_in[15];
  const float* attn_out_b = (const float*)d_in[17];
  const float* ln1_g = (const float*)d_in[18];
  const float* ln1_b = (const float*)d_in[19];
  const float* ln2_g = (const float*)d_in[20];
  const float* ln2_b = (const float*)d_in[21];
  const float* ff1_b = (const float*)d_in[23];
  const float* ff2_b = (const float*)d_in[25];
  const float* fc_b = (const float*)d_in[27];
  const float* out_b = (const float*)d_in[29];
  float* out = (float*)d_out;

  // ---- workspace layout (bf16 shorts first, then fp32) ----
  short* wsS = (short*)d_ws;
  size_t off = 0;
  auto alloc = [&](size_t n) { short* p = wsS + off; off += n; return p; };
  short* ewb0 = alloc(131072);    // 4*256*128
  short* ewb1 = alloc(262144);    // 4*256*256
  short* ewb2 = alloc(262144);
  short* aiwb = alloc(393216);    // 2*768*256
  short* aowb = alloc(131072);    // 2*256*256
  short* f1wb = alloc(1048576);   // 2*2048*256
  short* f2wb = alloc(1048576);   // 2*256*2048
  short* fcwb = alloc(65536);
  short* owb  = alloc(2560000);
  short* hb_e = alloc((size_t)S_ * E_);
  short* hb_a = alloc((size_t)S_ * H_);
  short* hb_b = alloc((size_t)S_ * H_);
  short* qkvb = alloc((size_t)S_ * 3 * H_);
  short* abufb = alloc((size_t)S_ * H_);
  short* tmpb = alloc((size_t)S_ * H_);      // aliased as Lpart (fp32) during attention
  short* ffhb = alloc((size_t)S_ * FF_);     // aliased as Opart (fp32) during attention
  float* vals = (float*)(wsS + off); off += 2 * (size_t)S_ * 2;
  int* sel = (int*)(wsS + off);
  float* Opart = (float*)ffhb;   // SPLITS_*NH_*S_*64 floats = S_*FF_*2 bytes, exact fit
  float* Lpart = (float*)tmpb;   // SPLITS_*NH_*S_ floats << S_*H_*2 bytes

  const short* moe_ewb[3] = {ewb0, ewb1, ewb2};

  // ---- weight pre-convert ----
  CvtArgs ca;
  ca.src[0] = (const float*)d_in[4];  ca.dst[0] = ewb0;
  ca.src[1] = (const float*)d_in[8];  ca.dst[1] = ewb1;
  ca.src[2] = (const float*)d_in[12]; ca.dst[2] = ewb2;
  ca.src[3] = (const float*)d_in[14]; ca.dst[3] = aiwb;
  ca.src[4] = (const float*)d_in[16]; ca.dst[4] = aowb;
  ca.src[5] = (const float*)d_in[22]; ca.dst[5] = f1wb;
  ca.src[6] = (const float*)d_in[24]; ca.dst[6] = f2wb;
  ca.src[7] = (const float*)d_in[26]; ca.dst[7] = fcwb;
  ca.src[8] = (const float*)d_in[28]; ca.dst[8] = owb;
  int sizes[9] = {131072, 262144, 262144, 393216, 131072, 1048576, 1048576, 65536, 2560000};
  ca.pfx[0] = 0;
  for (int i = 0; i < 9; ++i) ca.pfx[i + 1] = ca.pfx[i] + sizes[i] / 2048;
  k_cvt<<<dim3(ca.pfx[9]), dim3(256), 0, stream>>>(ca);

  k_embed<<<dim3(S_ * E_ / 1024), dim3(256), 0, stream>>>(x, emb, hb_e);

  // ---- MoE stack ----
  const short* moe_in[3] = {hb_e, hb_a, hb_b};
  short* moe_out[3] = {hb_a, hb_b, hb_a};
  int moe_k[3] = {E_, H_, H_};
  for (int i = 0; i < 3; ++i) {
    k_gates<<<dim3(S_ / 4), dim3(256), 0, stream>>>(moe_in[i], moe_k[i], moe_gw[i], moe_gb[i], vals, sel);
    k_moe<<<dim3(H_ / 64, S_ / 64), dim3(256), 0, stream>>>(moe_in[i], moe_ewb[i], moe_eb[i],
                                                            vals, sel, moe_out[i], H_, moe_k[i]);
  }

  // ---- transformer layers ----
  for (int l = 0; l < NL_; ++l) {
    k_gemm64<0><<<dim3(3 * H_ / 64, S_ / 64), dim3(256), 0, stream>>>(
        hb_a, aiwb + (size_t)l * 3 * H_ * H_, attn_in_b + (size_t)l * 3 * H_, qkvb, S_, 3 * H_, H_);
    k_attn<<<dim3(S_ / 64, NH_, SPLITS_), dim3(256), 0, stream>>>(qkvb, Opart, Lpart);
    k_att_combine<<<dim3(S_ * H_ / 256), dim3(256), 0, stream>>>(Opart, Lpart, abufb);
    k_gemm64<0><<<dim3(H_ / 64, S_ / 64), dim3(256), 0, stream>>>(
        abufb, aowb + (size_t)l * H_ * H_, attn_out_b + (size_t)l * H_, tmpb, S_, H_, H_);
    k_add_ln<<<dim3(S_), dim3(256), 0, stream>>>(hb_a, tmpb, ln1_g + l * H_, ln1_b + l * H_);
    k_gemm128<1, 0><<<dim3(FF_ / 128, S_ / 128), dim3(256), 0, stream>>>(
        hb_a, f1wb + (size_t)l * FF_ * H_, ff1_b + (size_t)l * FF_, ffhb, S_, FF_, H_);
    k_gemm64<0><<<dim3(H_ / 64, S_ / 64), dim3(256), 0, stream>>>(
        ffhb, f2wb + (size_t)l * H_ * FF_, ff2_b + (size_t)l * H_, tmpb, S_, H_, FF_);
    k_add_ln<<<dim3(S_), dim3(256), 0, stream>>>(hb_a, tmpb, ln2_g + l * H_, ln2_b + l * H_);
  }

  k_gemm64<0><<<dim3(H_ / 64, S_ / 64), dim3(256), 0, stream>>>(hb_a, fcwb, fc_b, tmpb, S_, H_, H_);
  k_gemm128<0, 1><<<dim3((V_ + 127) / 128, S_ / 128), dim3(256), 0, stream>>>(
      tmpb, owb, out_b, out, S_, V_, H_);
  k_logsoftmax<<<dim3(S_), dim3(256), 0, stream>>>(out);
}

// Round 4
// 639.369 us; speedup vs baseline: 3.2612x; 1.0411x over previous
//
#include <hip/hip_runtime.h>
#include <math.h>

#define S_ 4096
#define V_ 10000
#define E_ 128
#define H_ 256
#define NE_ 4
#define NH_ 4
#define HD_ 64
#define FF_ 2048
#define NL_ 2
#define EPS_ 1e-5f
#define SCALE_ 0.125f
#define SPLITS_ 4
#define PSTRIDE_ 160   // 79 col-blocks * 2 wave-halves = 158, padded

typedef __attribute__((ext_vector_type(8))) short bf16x8;
typedef __attribute__((ext_vector_type(4))) float f32x4;

static __device__ __forceinline__ short f2bf(float f) {
  unsigned u = __builtin_bit_cast(unsigned, f);
  unsigned r = (u + 0x7fffu + ((u >> 16) & 1u)) >> 16;
  return (short)r;
}
static __device__ __forceinline__ float bf2f(short s) {
  unsigned u = ((unsigned)(unsigned short)s) << 16;
  return __builtin_bit_cast(float, u);
}

// ---------------- weight fp32 -> bf16 pre-convert ----------------
struct CvtArgs {
  const float* src[9];
  short* dst[9];
  int pfx[10];
};
__global__ __launch_bounds__(256) void k_cvt(CvtArgs a) {
  int b = blockIdx.x, s = 0;
  while (b >= a.pfx[s + 1]) ++s;
  size_t base = (size_t)(b - a.pfx[s]) * 2048 + threadIdx.x * 8;
  const float* sp = a.src[s] + base;
  short* dp = a.dst[s] + base;
  float4 v0 = *(const float4*)sp;
  float4 v1 = *(const float4*)(sp + 4);
  short4 o0, o1;
  o0.x = f2bf(v0.x); o0.y = f2bf(v0.y); o0.z = f2bf(v0.z); o0.w = f2bf(v0.w);
  o1.x = f2bf(v1.x); o1.y = f2bf(v1.y); o1.z = f2bf(v1.z); o1.w = f2bf(v1.w);
  *(short4*)dp = o0;
  *(short4*)(dp + 4) = o1;
}

// ---------------- embedding gather -> bf16 ----------------
__global__ __launch_bounds__(256) void k_embed(const int* __restrict__ x,
                                               const float* __restrict__ emb,
                                               short* __restrict__ h) {
  int i4 = (blockIdx.x * 256 + threadIdx.x) * 4;
  int s = i4 >> 7, e = i4 & 127;
  float4 v = *(const float4*)&emb[(size_t)x[s] * E_ + e];
  short4 o;
  o.x = f2bf(v.x); o.y = f2bf(v.y); o.z = f2bf(v.z); o.w = f2bf(v.w);
  *(short4*)&h[i4] = o;
}

// ---------------- MoE gates ----------------
__global__ __launch_bounds__(256) void k_gates(const short* __restrict__ X, int din,
                                               const float* __restrict__ gw,
                                               const float* __restrict__ gb,
                                               float* __restrict__ vals,
                                               int* __restrict__ sel) {
  int wave = threadIdx.x >> 6, lane = threadIdx.x & 63;
  int s = blockIdx.x * 4 + wave;
  const short* xs = X + (size_t)s * din;
  float a0 = 0.f, a1 = 0.f, a2 = 0.f, a3 = 0.f;
  for (int i = lane; i < din; i += 64) {
    float xv = bf2f(xs[i]);
    a0 += xv * gw[0 * din + i];
    a1 += xv * gw[1 * din + i];
    a2 += xv * gw[2 * din + i];
    a3 += xv * gw[3 * din + i];
  }
#pragma unroll
  for (int off = 32; off > 0; off >>= 1) {
    a0 += __shfl_xor(a0, off, 64);
    a1 += __shfl_xor(a1, off, 64);
    a2 += __shfl_xor(a2, off, 64);
    a3 += __shfl_xor(a3, off, 64);
  }
  if (lane == 0) {
    float sc[4] = {a0 + gb[0], a1 + gb[1], a2 + gb[2], a3 + gb[3]};
    float mx = fmaxf(fmaxf(sc[0], sc[1]), fmaxf(sc[2], sc[3]));
    float sum = 0.f;
#pragma unroll
    for (int e = 0; e < 4; ++e) { sc[e] = expf(sc[e] - mx); sum += sc[e]; }
    float inv = 1.0f / sum;
#pragma unroll
    for (int e = 0; e < 4; ++e) sc[e] *= inv;
    int i0 = 0; float v0 = sc[0];
#pragma unroll
    for (int e = 1; e < 4; ++e) if (sc[e] > v0) { v0 = sc[e]; i0 = e; }
    float v1 = -1.0f; int i1 = 0;
#pragma unroll
    for (int e = 0; e < 4; ++e) if (e != i0 && sc[e] > v1) { v1 = sc[e]; i1 = e; }
    vals[2 * s + 0] = v0;
    vals[2 * s + 1] = v1;
    if (s == 0) { sel[0] = i0; sel[1] = i1; }
  }
}

// ---------------- 64x64-tile bf16 GEMM (qkv) ----------------
template <int ACT>
__global__ __launch_bounds__(256) void k_gemm64(const short* __restrict__ A,
                                                const short* __restrict__ W,
                                                const float* __restrict__ bias,
                                                short* __restrict__ C,
                                                int M, int N, int K) {
  __shared__ short As[64][40];
  __shared__ short Bs[64][40];
  int bm = blockIdx.y * 64, bn = blockIdx.x * 64;
  int tid = threadIdx.x, lane = tid & 63, wv = tid >> 6;
  int quad = lane >> 4, m16 = lane & 15;
  int wr = (wv >> 1) * 32, wc = (wv & 1) * 32;
  int srow = tid >> 2, sc = (tid & 3) * 8;
  const short* Ar = A + (size_t)(bm + srow) * K + sc;
  const short* Wr = W + (size_t)(bn + srow) * K + sc;
  f32x4 acc[2][2];
#pragma unroll
  for (int m = 0; m < 2; ++m)
#pragma unroll
    for (int n = 0; n < 2; ++n) acc[m][n] = (f32x4){0.f, 0.f, 0.f, 0.f};
  for (int k0 = 0; k0 < K; k0 += 32) {
    *(bf16x8*)&As[srow][sc] = *(const bf16x8*)&Ar[k0];
    *(bf16x8*)&Bs[srow][sc] = *(const bf16x8*)&Wr[k0];
    __syncthreads();
    bf16x8 af[2], bf[2];
#pragma unroll
    for (int m = 0; m < 2; ++m) af[m] = *(const bf16x8*)&As[wr + m * 16 + m16][quad * 8];
#pragma unroll
    for (int n = 0; n < 2; ++n) bf[n] = *(const bf16x8*)&Bs[wc + n * 16 + m16][quad * 8];
#pragma unroll
    for (int m = 0; m < 2; ++m)
#pragma unroll
      for (int n = 0; n < 2; ++n)
        acc[m][n] = __builtin_amdgcn_mfma_f32_16x16x32_bf16(af[m], bf[n], acc[m][n], 0, 0, 0);
    __syncthreads();
  }
#pragma unroll
  for (int n = 0; n < 2; ++n) {
    int col = bn + wc + n * 16 + m16;
    float b = bias[col];
#pragma unroll
    for (int m = 0; m < 2; ++m) {
      int row0 = bm + wr + m * 16 + quad * 4;
#pragma unroll
      for (int r = 0; r < 4; ++r) {
        float v = acc[m][n][r] + b;
        if (ACT) v = fmaxf(v, 0.f);
        C[(size_t)(row0 + r) * N + col] = f2bf(v);
      }
    }
  }
}

// ---------------- 32x64-tile bf16 GEMM (N=256 cases: proj/ff2/fc) ----------------
template <int ACT>
__global__ __launch_bounds__(256) void k_gemm32(const short* __restrict__ A,
                                                const short* __restrict__ W,
                                                const float* __restrict__ bias,
                                                short* __restrict__ C,
                                                int M, int N, int K) {
  __shared__ short As[32][40];
  __shared__ short Bs[64][40];
  int bm = blockIdx.y * 32, bn = blockIdx.x * 64;
  int tid = threadIdx.x, lane = tid & 63, wv = tid >> 6;
  int quad = lane >> 4, m16 = lane & 15;
  int wr = (wv >> 1) * 16, wc = (wv & 1) * 32;
  int srow = tid >> 2, sc = (tid & 3) * 8;
  const short* Ar = A + (size_t)(bm + (srow & 31)) * K + sc;
  const short* Wr = W + (size_t)(bn + srow) * K + sc;
  f32x4 acc[2];
  acc[0] = (f32x4){0.f, 0.f, 0.f, 0.f};
  acc[1] = (f32x4){0.f, 0.f, 0.f, 0.f};
  for (int k0 = 0; k0 < K; k0 += 32) {
    if (tid < 128) *(bf16x8*)&As[srow][sc] = *(const bf16x8*)&Ar[k0];
    *(bf16x8*)&Bs[srow][sc] = *(const bf16x8*)&Wr[k0];
    __syncthreads();
    bf16x8 af = *(const bf16x8*)&As[wr + m16][quad * 8];
    bf16x8 bf0 = *(const bf16x8*)&Bs[wc + m16][quad * 8];
    bf16x8 bf1 = *(const bf16x8*)&Bs[wc + 16 + m16][quad * 8];
    acc[0] = __builtin_amdgcn_mfma_f32_16x16x32_bf16(af, bf0, acc[0], 0, 0, 0);
    acc[1] = __builtin_amdgcn_mfma_f32_16x16x32_bf16(af, bf1, acc[1], 0, 0, 0);
    __syncthreads();
  }
#pragma unroll
  for (int n = 0; n < 2; ++n) {
    int col = bn + wc + n * 16 + m16;
    float b = bias[col];
    int row0 = bm + wr + quad * 4;
#pragma unroll
    for (int r = 0; r < 4; ++r) {
      float v = acc[n][r] + b;
      if (ACT) v = fmaxf(v, 0.f);
      C[(size_t)(row0 + r) * N + col] = f2bf(v);
    }
  }
}

// ---------------- MoE dual-expert 32x64 GEMM ----------------
__global__ __launch_bounds__(256) void k_moe(const short* __restrict__ A,
                                             const short* __restrict__ EW,
                                             const float* __restrict__ EB,
                                             const float* __restrict__ vals,
                                             const int* __restrict__ sel,
                                             short* __restrict__ C,
                                             int N, int K) {
  __shared__ short As[32][40];
  __shared__ short B0s[64][40];
  __shared__ short B1s[64][40];
  int e0 = sel[0], e1 = sel[1];
  const short* W0 = EW + (size_t)e0 * N * K;
  const short* W1 = EW + (size_t)e1 * N * K;
  const float* b0 = EB + (size_t)e0 * N;
  const float* b1 = EB + (size_t)e1 * N;
  int bm = blockIdx.y * 32, bn = blockIdx.x * 64;
  int tid = threadIdx.x, lane = tid & 63, wv = tid >> 6;
  int quad = lane >> 4, m16 = lane & 15;
  int wr = (wv >> 1) * 16, wc = (wv & 1) * 32;
  int srow = tid >> 2, sc = (tid & 3) * 8;
  const short* Ar = A + (size_t)(bm + (srow & 31)) * K + sc;
  const short* W0r = W0 + (size_t)(bn + srow) * K + sc;
  const short* W1r = W1 + (size_t)(bn + srow) * K + sc;
  f32x4 a0[2], a1[2];
  a0[0] = a0[1] = (f32x4){0.f, 0.f, 0.f, 0.f};
  a1[0] = a1[1] = (f32x4){0.f, 0.f, 0.f, 0.f};
  for (int k0 = 0; k0 < K; k0 += 32) {
    if (tid < 128) *(bf16x8*)&As[srow][sc] = *(const bf16x8*)&Ar[k0];
    *(bf16x8*)&B0s[srow][sc] = *(const bf16x8*)&W0r[k0];
    *(bf16x8*)&B1s[srow][sc] = *(const bf16x8*)&W1r[k0];
    __syncthreads();
    bf16x8 af = *(const bf16x8*)&As[wr + m16][quad * 8];
#pragma unroll
    for (int n = 0; n < 2; ++n) {
      bf16x8 bf0 = *(const bf16x8*)&B0s[wc + n * 16 + m16][quad * 8];
      bf16x8 bf1 = *(const bf16x8*)&B1s[wc + n * 16 + m16][quad * 8];
      a0[n] = __builtin_amdgcn_mfma_f32_16x16x32_bf16(af, bf0, a0[n], 0, 0, 0);
      a1[n] = __builtin_amdgcn_mfma_f32_16x16x32_bf16(af, bf1, a1[n], 0, 0, 0);
    }
    __syncthreads();
  }
#pragma unroll
  for (int n = 0; n < 2; ++n) {
    int col = bn + wc + n * 16 + m16;
    float bb0 = b0[col], bb1 = b1[col];
    int row0 = bm + wr + quad * 4;
#pragma unroll
    for (int r = 0; r < 4; ++r) {
      int row = row0 + r;
      float v = vals[2 * row] * (a0[n][r] + bb0) + vals[2 * row + 1] * (a1[n][r] + bb1);
      C[(size_t)row * N + col] = f2bf(v);
    }
  }
}

// ---------------- 128x128-tile bf16 GEMM (ff1) ----------------
template <int ACT>
__global__ __launch_bounds__(256) void k_gemm128(const short* __restrict__ A,
                                                 const short* __restrict__ W,
                                                 const float* __restrict__ bias,
                                                 short* __restrict__ C,
                                                 int M, int N, int K) {
  __shared__ short As[128][40];
  __shared__ short Bs[128][40];
  int bm = blockIdx.y * 128, bn = blockIdx.x * 128;
  int tid = threadIdx.x, lane = tid & 63, wv = tid >> 6;
  int quad = lane >> 4, m16 = lane & 15;
  int wr = (wv >> 1) * 64, wc = (wv & 1) * 64;
  int srow = tid >> 1, sc = (tid & 1) * 16;
  const short* Ar = A + (size_t)(bm + srow) * K + sc;
  const short* Wr = W + (size_t)(bn + srow) * K + sc;
  f32x4 acc[4][4];
#pragma unroll
  for (int m = 0; m < 4; ++m)
#pragma unroll
    for (int n = 0; n < 4; ++n) acc[m][n] = (f32x4){0.f, 0.f, 0.f, 0.f};
  for (int k0 = 0; k0 < K; k0 += 32) {
    *(bf16x8*)&As[srow][sc] = *(const bf16x8*)&Ar[k0];
    *(bf16x8*)&As[srow][sc + 8] = *(const bf16x8*)&Ar[k0 + 8];
    *(bf16x8*)&Bs[srow][sc] = *(const bf16x8*)&Wr[k0];
    *(bf16x8*)&Bs[srow][sc + 8] = *(const bf16x8*)&Wr[k0 + 8];
    __syncthreads();
    bf16x8 af[4], bf[4];
#pragma unroll
    for (int m = 0; m < 4; ++m) af[m] = *(const bf16x8*)&As[wr + m * 16 + m16][quad * 8];
#pragma unroll
    for (int n = 0; n < 4; ++n) bf[n] = *(const bf16x8*)&Bs[wc + n * 16 + m16][quad * 8];
#pragma unroll
    for (int m = 0; m < 4; ++m)
#pragma unroll
      for (int n = 0; n < 4; ++n)
        acc[m][n] = __builtin_amdgcn_mfma_f32_16x16x32_bf16(af[m], bf[n], acc[m][n], 0, 0, 0);
    __syncthreads();
  }
#pragma unroll
  for (int n = 0; n < 4; ++n) {
    int col = bn + wc + n * 16 + m16;
    float b = bias[col];
#pragma unroll
    for (int m = 0; m < 4; ++m) {
      int row0 = bm + wr + m * 16 + quad * 4;
#pragma unroll
      for (int r = 0; r < 4; ++r) {
        float v = acc[m][n][r] + b;
        if (ACT) v = fmaxf(v, 0.f);
        C[(size_t)(row0 + r) * N + col] = f2bf(v);
      }
    }
  }
}

// ---------------- logits GEMM: fp32 out + per-row partial sum of exp -> psums ----------------
__global__ __launch_bounds__(256) void k_glogits(const short* __restrict__ A,
                                                 const short* __restrict__ W,
                                                 const float* __restrict__ bias,
                                                 float* __restrict__ C,
                                                 float* __restrict__ psums,
                                                 int M, int N, int K) {
  __shared__ short As[128][40];
  __shared__ short Bs[128][40];
  int bm = blockIdx.y * 128, bn = blockIdx.x * 128;
  int tid = threadIdx.x, lane = tid & 63, wv = tid >> 6;
  int quad = lane >> 4, m16 = lane & 15;
  int wr = (wv >> 1) * 64, wc = (wv & 1) * 64;
  int srow = tid >> 1, sc = (tid & 1) * 16;
  const short* Ar = A + (size_t)(bm + srow) * K + sc;
  int br = bn + srow;
  const short* Wr = W + (size_t)(br < N ? br : N - 1) * K + sc;
  f32x4 acc[4][4];
#pragma unroll
  for (int m = 0; m < 4; ++m)
#pragma unroll
    for (int n = 0; n < 4; ++n) acc[m][n] = (f32x4){0.f, 0.f, 0.f, 0.f};
  for (int k0 = 0; k0 < K; k0 += 32) {
    *(bf16x8*)&As[srow][sc] = *(const bf16x8*)&Ar[k0];
    *(bf16x8*)&As[srow][sc + 8] = *(const bf16x8*)&Ar[k0 + 8];
    *(bf16x8*)&Bs[srow][sc] = *(const bf16x8*)&Wr[k0];
    *(bf16x8*)&Bs[srow][sc + 8] = *(const bf16x8*)&Wr[k0 + 8];
    __syncthreads();
    bf16x8 af[4], bf[4];
#pragma unroll
    for (int m = 0; m < 4; ++m) af[m] = *(const bf16x8*)&As[wr + m * 16 + m16][quad * 8];
#pragma unroll
    for (int n = 0; n < 4; ++n) bf[n] = *(const bf16x8*)&Bs[wc + n * 16 + m16][quad * 8];
#pragma unroll
    for (int m = 0; m < 4; ++m)
#pragma unroll
      for (int n = 0; n < 4; ++n)
        acc[m][n] = __builtin_amdgcn_mfma_f32_16x16x32_bf16(af[m], bf[n], acc[m][n], 0, 0, 0);
    __syncthreads();
  }
  // bias per n-column (guard edge block)
  float bcol[4];
  int cvalid[4];
#pragma unroll
  for (int n = 0; n < 4; ++n) {
    int col = bn + wc + n * 16 + m16;
    cvalid[n] = (col < N);
    bcol[n] = cvalid[n] ? bias[col] : 0.f;
  }
  int pslot = blockIdx.x * 2 + (wv & 1);
#pragma unroll
  for (int m = 0; m < 4; ++m) {
#pragma unroll
    for (int r = 0; r < 4; ++r) {
      int row = bm + wr + m * 16 + quad * 4 + r;
      float es = 0.f;
#pragma unroll
      for (int n = 0; n < 4; ++n) {
        if (cvalid[n]) {
          float v = acc[m][n][r] + bcol[n];
          C[(size_t)row * N + (bn + wc + n * 16 + m16)] = v;
          es += __expf(v);
        }
      }
#pragma unroll
      for (int mask = 1; mask < 16; mask <<= 1) es += __shfl_xor(es, mask, 16);
      if (m16 == 0) psums[(size_t)row * PSTRIDE_ + pslot] = es;
    }
  }
}

// ---------------- finalize log-softmax: lse from psums, out -= lse ----------------
__global__ __launch_bounds__(256) void k_lsfinal(float* __restrict__ out,
                                                 const float* __restrict__ psums,
                                                 int nslots) {
  __shared__ float rbuf[256];
  int s = blockIdx.x, t = threadIdx.x;
  rbuf[t] = (t < nslots) ? psums[(size_t)s * PSTRIDE_ + t] : 0.f;
  __syncthreads();
#pragma unroll
  for (int o = 128; o > 0; o >>= 1) {
    if (t < o) rbuf[t] += rbuf[t + o];
    __syncthreads();
  }
  float lse = logf(rbuf[0]);
  float4* row = (float4*)(out + (size_t)s * V_);
  for (int i = t; i < V_ / 4; i += 256) {
    float4 o4 = row[i];
    o4.x -= lse; o4.y -= lse; o4.z -= lse; o4.w -= lse;
    row[i] = o4;
  }
}

// ---------------- bf16-MFMA flash attention, KV-split ----------------
__global__ __launch_bounds__(256) void k_attn(const short* __restrict__ qkv,
                                              float* __restrict__ Opart,
                                              float* __restrict__ Lpart) {
  __shared__ short Ks[64][72];
  __shared__ short Vt[64][72];
  __shared__ short Ps[4][16][88];
  int tid = threadIdx.x, lane = tid & 63, wv = tid >> 6;
  int quad = lane >> 4, m16 = lane & 15;
  int head = blockIdx.y, hd0 = head * HD_;
  int split = blockIdx.z;
  int qbase = blockIdx.x * 64 + wv * 16;
  bf16x8 qf[2];
  {
    const short* qr = qkv + (size_t)(qbase + m16) * (3 * H_) + hd0 + quad * 8;
    qf[0] = *(const bf16x8*)&qr[0];
    qf[1] = *(const bf16x8*)&qr[32];
  }
  f32x4 o[4];
#pragma unroll
  for (int dt = 0; dt < 4; ++dt) o[dt] = (f32x4){0.f, 0.f, 0.f, 0.f};
  float l[4] = {0.f, 0.f, 0.f, 0.f};

  int kb_end = (split + 1) * (S_ / 64 / SPLITS_);
  for (int kb = split * (S_ / 64 / SPLITS_); kb < kb_end; ++kb) {
    __syncthreads();
    {
      int key = tid >> 2, d0 = (tid & 3) * 16;
      const short* kr = qkv + (size_t)(kb * 64 + key) * (3 * H_) + H_ + hd0 + d0;
      *(bf16x8*)&Ks[key][d0] = *(const bf16x8*)&kr[0];
      *(bf16x8*)&Ks[key][d0 + 8] = *(const bf16x8*)&kr[8];
    }
    {
      int key0 = (tid & 15) * 4, d0 = (tid >> 4) * 4;
      const short* vbase = qkv + (size_t)(kb * 64 + key0) * (3 * H_) + 2 * H_ + hd0 + d0;
      short4 v0 = *(const short4*)&vbase[0];
      short4 v1 = *(const short4*)&vbase[3 * H_];
      short4 v2 = *(const short4*)&vbase[6 * H_];
      short4 v3 = *(const short4*)&vbase[9 * H_];
      short4 t0 = {v0.x, v1.x, v2.x, v3.x};
      short4 t1 = {v0.y, v1.y, v2.y, v3.y};
      short4 t2 = {v0.z, v1.z, v2.z, v3.z};
      short4 t3 = {v0.w, v1.w, v2.w, v3.w};
      *(short4*)&Vt[d0 + 0][key0] = t0;
      *(short4*)&Vt[d0 + 1][key0] = t1;
      *(short4*)&Vt[d0 + 2][key0] = t2;
      *(short4*)&Vt[d0 + 3][key0] = t3;
    }
    __syncthreads();
    f32x4 s4[4];
#pragma unroll
    for (int kt = 0; kt < 4; ++kt) {
      bf16x8 bk0 = *(const bf16x8*)&Ks[kt * 16 + m16][quad * 8];
      bf16x8 bk1 = *(const bf16x8*)&Ks[kt * 16 + m16][32 + quad * 8];
      f32x4 z = (f32x4){0.f, 0.f, 0.f, 0.f};
      z = __builtin_amdgcn_mfma_f32_16x16x32_bf16(qf[0], bk0, z, 0, 0, 0);
      z = __builtin_amdgcn_mfma_f32_16x16x32_bf16(qf[1], bk1, z, 0, 0, 0);
      s4[kt] = z;
    }
    f32x4 rs = (f32x4){0.f, 0.f, 0.f, 0.f};
#pragma unroll
    for (int kt = 0; kt < 4; ++kt) {
#pragma unroll
      for (int r = 0; r < 4; ++r) {
        float p = __expf(s4[kt][r] * SCALE_);
        rs[r] += p;
        Ps[wv][quad * 4 + r][kt * 16 + m16] = f2bf(p);
      }
    }
#pragma unroll
    for (int mask = 1; mask < 16; mask <<= 1) {
      rs[0] += __shfl_xor(rs[0], mask, 16);
      rs[1] += __shfl_xor(rs[1], mask, 16);
      rs[2] += __shfl_xor(rs[2], mask, 16);
      rs[3] += __shfl_xor(rs[3], mask, 16);
    }
#pragma unroll
    for (int r = 0; r < 4; ++r) l[r] += rs[r];
#pragma unroll
    for (int c = 0; c < 2; ++c) {
      bf16x8 pa = *(const bf16x8*)&Ps[wv][m16][c * 32 + quad * 8];
#pragma unroll
      for (int dt = 0; dt < 4; ++dt) {
        bf16x8 bv = *(const bf16x8*)&Vt[dt * 16 + m16][c * 32 + quad * 8];
        o[dt] = __builtin_amdgcn_mfma_f32_16x16x32_bf16(pa, bv, o[dt], 0, 0, 0);
      }
    }
  }
  float* Op = Opart + ((size_t)(split * NH_ + head) * S_) * 64;
#pragma unroll
  for (int dt = 0; dt < 4; ++dt) {
#pragma unroll
    for (int r = 0; r < 4; ++r) {
      int row = qbase + quad * 4 + r;
      Op[(size_t)row * 64 + dt * 16 + m16] = o[dt][r];
    }
  }
  if (m16 == 0) {
    float* Lp = Lpart + (size_t)(split * NH_ + head) * S_;
#pragma unroll
    for (int r = 0; r < 4; ++r) Lp[qbase + quad * 4 + r] = l[r];
  }
}

// ---------------- combine split partials -> abuf bf16 ----------------
__global__ __launch_bounds__(256) void k_att_combine(const float* __restrict__ Opart,
                                                     const float* __restrict__ Lpart,
                                                     short* __restrict__ abuf) {
  int idx = blockIdx.x * 256 + threadIdx.x;
  int s = idx >> 8, hd = idx & 255;
  int head = hd >> 6, d = hd & 63;
  float num = 0.f, den = 0.f;
#pragma unroll
  for (int sp = 0; sp < SPLITS_; ++sp) {
    num += Opart[((size_t)(sp * NH_ + head) * S_ + s) * 64 + d];
    den += Lpart[(size_t)(sp * NH_ + head) * S_ + s];
  }
  abuf[idx] = f2bf(num / den);
}

// ---------------- h = LN(h + t) * g + b, wave-per-row ----------------
__global__ __launch_bounds__(256) void k_add_ln(short* __restrict__ h,
                                                const short* __restrict__ t_,
                                                const float* __restrict__ g,
                                                const float* __restrict__ b) {
  int wv = threadIdx.x >> 6, lane = threadIdx.x & 63;
  int s = blockIdx.x * 4 + wv;
  size_t off = (size_t)s * H_ + lane * 4;
  short4 hv = *(const short4*)&h[off];
  short4 tv = *(const short4*)&t_[off];
  float x[4] = {bf2f(hv.x) + bf2f(tv.x), bf2f(hv.y) + bf2f(tv.y),
                bf2f(hv.z) + bf2f(tv.z), bf2f(hv.w) + bf2f(tv.w)};
  float sum = x[0] + x[1] + x[2] + x[3];
#pragma unroll
  for (int mask = 1; mask < 64; mask <<= 1) sum += __shfl_xor(sum, mask, 64);
  float mean = sum * (1.0f / H_);
  float d[4], vs = 0.f;
#pragma unroll
  for (int i = 0; i < 4; ++i) { d[i] = x[i] - mean; vs += d[i] * d[i]; }
#pragma unroll
  for (int mask = 1; mask < 64; mask <<= 1) vs += __shfl_xor(vs, mask, 64);
  float inv = rsqrtf(vs * (1.0f / H_) + EPS_);
  float4 gv = *(const float4*)&g[lane * 4];
  float4 bv = *(const float4*)&b[lane * 4];
  short4 ov;
  ov.x = f2bf(d[0] * inv * gv.x + bv.x);
  ov.y = f2bf(d[1] * inv * gv.y + bv.y);
  ov.z = f2bf(d[2] * inv * gv.z + bv.z);
  ov.w = f2bf(d[3] * inv * gv.w + bv.w);
  *(short4*)&h[off] = ov;
}

extern "C" void kernel_launch(void* const* d_in, const int* in_sizes, int n_in,
                              void* d_out, int out_size, void* d_ws, size_t ws_size,
                              hipStream_t stream) {
  const int* x = (const int*)d_in[0];
  const float* emb = (const float*)d_in[1];
  const float* moe_gw[3] = {(const float*)d_in[2], (const float*)d_in[6], (const float*)d_in[10]};
  const float* moe_gb[3] = {(const float*)d_in[3], (const float*)d_in[7], (const float*)d_in[11]};
  const float* moe_eb[3] = {(const float*)d_in[5], (const float*)d_in[9], (const float*)d_in[13]};
  const float* attn_in_b = (const float*)d_in[15];
  const float* attn_out_b = (const float*)d_in[17];
  const float* ln1_g = (const float*)d_in[18];
  const float* ln1_b = (const float*)d_in[19];
  const float* ln2_g = (const float*)d_in[20];
  const float* ln2_b = (const float*)d_in[21];
  const float* ff1_b = (const float*)d_in[23];
  const float* ff2_b = (const float*)d_in[25];
  const float* fc_b = (const float*)d_in[27];
  const float* out_b = (const float*)d_in[29];
  float* out = (float*)d_out;

  short* wsS = (short*)d_ws;
  size_t off = 0;
  auto alloc = [&](size_t n) { short* p = wsS + off; off += n; return p; };
  short* ewb0 = alloc(131072);
  short* ewb1 = alloc(262144);
  short* ewb2 = alloc(262144);
  short* aiwb = alloc(393216);
  short* aowb = alloc(131072);
  short* f1wb = alloc(1048576);   // after layers: psums aliases f1wb+f2wb (4 MB >= 2.62 MB)
  short* f2wb = alloc(1048576);
  short* fcwb = alloc(65536);
  short* owb  = alloc(2560000);
  short* hb_e = alloc((size_t)S_ * E_);
  short* hb_a = alloc((size_t)S_ * H_);
  short* hb_b = alloc((size_t)S_ * H_);
  short* qkvb = alloc((size_t)S_ * 3 * H_);
  short* abufb = alloc((size_t)S_ * H_);
  short* tmpb = alloc((size_t)S_ * H_);      // aliased as Lpart during attention
  short* ffhb = alloc((size_t)S_ * FF_);     // aliased as Opart during attention
  float* vals = (float*)(wsS + off); off += 2 * (size_t)S_ * 2;
  int* sel = (int*)(wsS + off);
  float* Opart = (float*)ffhb;
  float* Lpart = (float*)tmpb;
  float* psums = (float*)f1wb;   // used only after all layers done

  const short* moe_ewb[3] = {ewb0, ewb1, ewb2};

  CvtArgs ca;
  ca.src[0] = (const float*)d_in[4];  ca.dst[0] = ewb0;
  ca.src[1] = (const float*)d_in[8];  ca.dst[1] = ewb1;
  ca.src[2] = (const float*)d_in[12]; ca.dst[2] = ewb2;
  ca.src[3] = (const float*)d_in[14]; ca.dst[3] = aiwb;
  ca.src[4] = (const float*)d_in[16]; ca.dst[4] = aowb;
  ca.src[5] = (const float*)d_in[22]; ca.dst[5] = f1wb;
  ca.src[6] = (const float*)d_in[24]; ca.dst[6] = f2wb;
  ca.src[7] = (const float*)d_in[26]; ca.dst[7] = fcwb;
  ca.src[8] = (const float*)d_in[28]; ca.dst[8] = owb;
  int sizes[9] = {131072, 262144, 262144, 393216, 131072, 1048576, 1048576, 65536, 2560000};
  ca.pfx[0] = 0;
  for (int i = 0; i < 9; ++i) ca.pfx[i + 1] = ca.pfx[i] + sizes[i] / 2048;
  k_cvt<<<dim3(ca.pfx[9]), dim3(256), 0, stream>>>(ca);

  k_embed<<<dim3(S_ * E_ / 1024), dim3(256), 0, stream>>>(x, emb, hb_e);

  const short* moe_in[3] = {hb_e, hb_a, hb_b};
  short* moe_out[3] = {hb_a, hb_b, hb_a};
  int moe_k[3] = {E_, H_, H_};
  for (int i = 0; i < 3; ++i) {
    k_gates<<<dim3(S_ / 4), dim3(256), 0, stream>>>(moe_in[i], moe_k[i], moe_gw[i], moe_gb[i], vals, sel);
    k_moe<<<dim3(H_ / 64, S_ / 32), dim3(256), 0, stream>>>(moe_in[i], moe_ewb[i], moe_eb[i],
                                                            vals, sel, moe_out[i], H_, moe_k[i]);
  }

  for (int l = 0; l < NL_; ++l) {
    k_gemm64<0><<<dim3(3 * H_ / 64, S_ / 64), dim3(256), 0, stream>>>(
        hb_a, aiwb + (size_t)l * 3 * H_ * H_, attn_in_b + (size_t)l * 3 * H_, qkvb, S_, 3 * H_, H_);
    k_attn<<<dim3(S_ / 64, NH_, SPLITS_), dim3(256), 0, stream>>>(qkvb, Opart, Lpart);
    k_att_combine<<<dim3(S_ * H_ / 256), dim3(256), 0, stream>>>(Opart, Lpart, abufb);
    k_gemm32<0><<<dim3(H_ / 64, S_ / 32), dim3(256), 0, stream>>>(
        abufb, aowb + (size_t)l * H_ * H_, attn_out_b + (size_t)l * H_, tmpb, S_, H_, H_);
    k_add_ln<<<dim3(S_ / 4), dim3(256), 0, stream>>>(hb_a, tmpb, ln1_g + l * H_, ln1_b + l * H_);
    k_gemm128<1><<<dim3(FF_ / 128, S_ / 128), dim3(256), 0, stream>>>(
        hb_a, f1wb + (size_t)l * FF_ * H_, ff1_b + (size_t)l * FF_, ffhb, S_, FF_, H_);
    k_gemm32<0><<<dim3(H_ / 64, S_ / 32), dim3(256), 0, stream>>>(
        ffhb, f2wb + (size_t)l * H_ * FF_, ff2_b + (size_t)l * H_, tmpb, S_, H_, FF_);
    k_add_ln<<<dim3(S_ / 4), dim3(256), 0, stream>>>(hb_a, tmpb, ln2_g + l * H_, ln2_b + l * H_);
  }

  k_gemm32<0><<<dim3(H_ / 64, S_ / 32), dim3(256), 0, stream>>>(hb_a, fcwb, fc_b, tmpb, S_, H_, H_);
  int nxb = (V_ + 127) / 128;  // 79
  k_glogits<<<dim3(nxb, S_ / 128), dim3(256), 0, stream>>>(tmpb, owb, out_b, out, psums, S_, V_, H_);
  k_lsfinal<<<dim3(S_), dim3(256), 0, stream>>>(out, psums, nxb * 2);
}